// Round 10
// baseline (702.297 us; speedup 1.0000x reference)
//
#include <hip/hip_runtime.h>
#include <math.h>

typedef __attribute__((ext_vector_type(8))) short bf16x8;
typedef __attribute__((ext_vector_type(4))) float f32x4;
typedef __attribute__((ext_vector_type(16))) float f32x16;

#define NB 4
#define NL 2048
#define ND 2048
#define NH 16
#define NDH 128
#define NDC 512
#define NROWS (NB*NL)

__device__ __forceinline__ unsigned short f2bf(float f) {
  unsigned int u = __float_as_uint(f);
  u += 0x7fffu + ((u >> 16) & 1u);
  return (unsigned short)(u >> 16);
}
__device__ __forceinline__ float bf2f(unsigned short h) {
  return __uint_as_float(((unsigned int)h) << 16);
}
__device__ __forceinline__ unsigned int cvtpk(float lo, float hi) {
  unsigned int r;
  asm("v_cvt_pk_bf16_f32 %0, %1, %2" : "=v"(r) : "v"(lo), "v"(hi));
  return r;
}
// v_permlane32_swap_b32: a.lanes[32:63] <-> b.lanes[0:31]
__device__ __forceinline__ void permswap(unsigned int &a, unsigned int &b) {
  asm("v_permlane32_swap_b32 %0, %1" : "+v"(a), "+v"(b));
}
__device__ __forceinline__ float exp2_fast(float x) {
  float r; asm("v_exp_f32 %0, %1" : "=v"(r) : "v"(x)); return r;
}

__device__ __forceinline__ void gld16(const void* g, void* l) {
  __builtin_amdgcn_global_load_lds((const __attribute__((address_space(1))) void*)g,
                                   (__attribute__((address_space(3))) void*)l, 16, 0, 0);
}

// ---------------- fp32 -> bf16 convert ----------------
__global__ void cvt_kernel(const float4* __restrict__ in, ushort4* __restrict__ out, int n4) {
  int stride = gridDim.x * blockDim.x;
  for (int i = blockIdx.x * blockDim.x + threadIdx.x; i < n4; i += stride) {
    float4 v = in[i];
    ushort4 o;
    o.x = f2bf(v.x); o.y = f2bf(v.y); o.z = f2bf(v.z); o.w = f2bf(v.w);
    out[i] = o;
  }
}

// ---------------- 128^2 NT GEMM (kept for N=512 shapes) ----------------
template<int OUT_F32>
__global__ __launch_bounds__(256) void gemm_nt(const unsigned short* __restrict__ A,
                                               const unsigned short* __restrict__ Bm,
                                               void* __restrict__ Cv,
                                               int M, int N, int K) {
  __shared__ unsigned short As[128 * 32];
  __shared__ unsigned short Bs[128 * 32];
  const int tid = threadIdx.x;
  const int wid = tid >> 6;
  const int lane = tid & 63;
  const int wr = wid >> 1, wc = wid & 1;
  const long bm = blockIdx.y, bn = blockIdx.x;
  const int r15 = lane & 15;
  const int koff = (lane >> 4) * 8;
  const int srow = lane >> 2;
  const int scol = (lane & 3) * 8;

  f32x4 acc[4][4];
#pragma unroll
  for (int m = 0; m < 4; ++m)
#pragma unroll
    for (int n = 0; n < 4; ++n) acc[m][n] = (f32x4){0.f, 0.f, 0.f, 0.f};

  const unsigned short* Ablk = A + (bm * 128 + wid * 16 + srow) * (long)K + scol;
  const unsigned short* Bblk = Bm + (bn * 128 + wid * 16 + srow) * (long)K + scol;
  unsigned short* AsW = As + wid * 16 * 32;
  unsigned short* BsW = Bs + wid * 16 * 32;

  for (int kk = 0; kk < K; kk += 32) {
    __syncthreads();
#pragma unroll
    for (int j = 0; j < 2; ++j) {
      gld16(Ablk + (long)j * 64 * K + kk, AsW + j * 64 * 32);
      gld16(Bblk + (long)j * 64 * K + kk, BsW + j * 64 * 32);
    }
    __syncthreads();
    bf16x8 af[4], bfr[4];
#pragma unroll
    for (int m = 0; m < 4; ++m)
      af[m] = *(const bf16x8*)(As + (wr * 64 + m * 16 + r15) * 32 + koff);
#pragma unroll
    for (int n = 0; n < 4; ++n)
      bfr[n] = *(const bf16x8*)(Bs + (wc * 64 + n * 16 + r15) * 32 + koff);
#pragma unroll
    for (int m = 0; m < 4; ++m)
#pragma unroll
      for (int n = 0; n < 4; ++n)
        acc[m][n] = __builtin_amdgcn_mfma_f32_16x16x32_bf16(af[m], bfr[n], acc[m][n], 0, 0, 0);
  }

  const int rr = (lane >> 4) * 4;
#pragma unroll
  for (int m = 0; m < 4; ++m) {
#pragma unroll
    for (int n = 0; n < 4; ++n) {
      long row0 = bm * 128 + wr * 64 + m * 16 + rr;
      long col = bn * 128 + wc * 64 + n * 16 + r15;
#pragma unroll
      for (int r = 0; r < 4; ++r) {
        float v = acc[m][n][r];
        if (OUT_F32) ((float*)Cv)[(row0 + r) * (long)N + col] = v;
        else ((unsigned short*)Cv)[(row0 + r) * (long)N + col] = f2bf(v);
      }
    }
  }
}

// ---------------- 256^2 8-phase NT GEMM (T1+T2+T3+T4+T5) ----------------
template<int OUT_F32>
__global__ __launch_bounds__(512) void gemm_nt256(const unsigned short* __restrict__ A,
                                                  const unsigned short* __restrict__ Bm,
                                                  void* __restrict__ Cv,
                                                  int M, int N, int K) {
  __shared__ unsigned short lds[2][2][16384];   // [buf][0=A,1=B][256 rows x 64 cols]
  const int tid = threadIdx.x;
  const int wid = tid >> 6, lane = tid & 63;
  const int wm = wid >> 2, wn = wid & 3;
  const int r15 = lane & 15, khi = lane >> 4;

  const int gx = gridDim.x;
  int bid = blockIdx.y * gx + blockIdx.x;
  int cpx = (gx * gridDim.y) >> 3;
  int swz = (bid & 7) * cpx + (bid >> 3);
  const long bm = swz / gx, bn = swz % gx;

  const int c0 = tid, c1 = 512 + tid;
  const int r0 = c0 >> 3, r1 = c1 >> 3;
  const int cs0 = ((c0 & 7) ^ (r0 & 7)) * 8;
  const int cs1 = ((c1 & 7) ^ (r1 & 7)) * 8;
  const unsigned short* srcA = A + (bm * 256) * (long)K;
  const unsigned short* srcB = Bm + (bn * 256) * (long)K;

#define STAGE256(mat, h, kb, bufi) do {                                              \
    const unsigned short* s_ = (mat) ? srcB : srcA;                                  \
    gld16(s_ + ((h) * 128 + r0) * (long)K + (kb) + cs0,                              \
          &lds[bufi][mat][(h) * 8192 + wid * 512]);                                  \
    gld16(s_ + ((h) * 128 + r1) * (long)K + (kb) + cs1,                              \
          &lds[bufi][mat][(h) * 8192 + 4096 + wid * 512]);                           \
  } while (0)

  f32x4 acc[8][4];
#pragma unroll
  for (int m = 0; m < 8; ++m)
#pragma unroll
    for (int n = 0; n < 4; ++n) acc[m][n] = (f32x4){0.f, 0.f, 0.f, 0.f};

  const int NT = K >> 6;
  STAGE256(0, 0, 0, 0); STAGE256(0, 1, 0, 0);
  STAGE256(1, 0, 0, 0); STAGE256(1, 1, 0, 0);

  for (int t = 0; t < NT; ++t) {
    const int buf = t & 1, nbuf = buf ^ 1;
    const int kb1 = (t + 1) << 6;
    const bool pf = (t + 1 < NT);
    __builtin_amdgcn_s_barrier();
    if (pf) {
      STAGE256(0, 0, kb1, nbuf);
      asm volatile("s_waitcnt vmcnt(2)" ::: "memory");
    } else {
      asm volatile("s_waitcnt vmcnt(0)" ::: "memory");
    }
    __builtin_amdgcn_s_barrier();

    bf16x8 bfr[4][2];
#pragma unroll
    for (int n = 0; n < 4; ++n)
#pragma unroll
      for (int kk = 0; kk < 2; ++kk) {
        int rb = wn * 64 + n * 16 + r15;
        bfr[n][kk] = *(const bf16x8*)&lds[buf][1][rb * 64 + (((kk * 4 + khi) ^ (rb & 7)) * 8)];
      }
#pragma unroll
    for (int mb = 0; mb < 4; ++mb) {
      if (mb != 0) {
        __builtin_amdgcn_s_barrier();
        if (pf) {
          if (mb == 1) STAGE256(0, 1, kb1, nbuf);
          else if (mb == 2) STAGE256(1, 0, kb1, nbuf);
          else STAGE256(1, 1, kb1, nbuf);
        }
      }
      bf16x8 af[2][2];
#pragma unroll
      for (int m2 = 0; m2 < 2; ++m2)
#pragma unroll
        for (int kk = 0; kk < 2; ++kk) {
          int ra = wm * 128 + mb * 32 + m2 * 16 + r15;
          af[m2][kk] = *(const bf16x8*)&lds[buf][0][ra * 64 + (((kk * 4 + khi) ^ (ra & 7)) * 8)];
        }
      asm volatile("s_waitcnt lgkmcnt(0)" ::: "memory");
      __builtin_amdgcn_sched_barrier(0);
      __builtin_amdgcn_s_setprio(1);
#pragma unroll
      for (int m2 = 0; m2 < 2; ++m2)
#pragma unroll
        for (int n = 0; n < 4; ++n)
#pragma unroll
          for (int kk = 0; kk < 2; ++kk)
            acc[mb * 2 + m2][n] = __builtin_amdgcn_mfma_f32_16x16x32_bf16(
                af[m2][kk], bfr[n][kk], acc[mb * 2 + m2][n], 0, 0, 0);
      __builtin_amdgcn_s_setprio(0);
    }
  }
#undef STAGE256

#pragma unroll
  for (int mi = 0; mi < 8; ++mi) {
#pragma unroll
    for (int n = 0; n < 4; ++n) {
      long row0 = bm * 256 + wm * 128 + mi * 16 + khi * 4;
      long col = bn * 256 + wn * 64 + n * 16 + r15;
#pragma unroll
      for (int r = 0; r < 4; ++r) {
        float v = acc[mi][n][r];
        if (OUT_F32) ((float*)Cv)[(row0 + r) * (long)N + col] = v;
        else ((unsigned short*)Cv)[(row0 + r) * (long)N + col] = f2bf(v);
      }
    }
  }
}

// ---------------- RoPE in-place (vectorized: 8 pairs/thread, bf16x8 loads) ----------------
__global__ void rope_kernel(unsigned short* __restrict__ Qb, const float* __restrict__ cosb,
                            const float* __restrict__ sinb, float scale) {
  const long row = blockIdx.x;
  const int p = threadIdx.x;            // 0..127
  const int h = p >> 3, d8 = (p & 7) * 8;
  const float* cr = cosb + row * NDH;
  const float* sr = sinb + row * NDH;
  unsigned short* q = Qb + row * (long)ND + h * 128 + d8;

  bf16x8 qlo = *(const bf16x8*)(q);
  bf16x8 qhi = *(const bf16x8*)(q + 64);
  float4 c0 = *(const float4*)(cr + d8), c1 = *(const float4*)(cr + d8 + 4);
  float4 c2 = *(const float4*)(cr + d8 + 64), c3 = *(const float4*)(cr + d8 + 68);
  float4 s0 = *(const float4*)(sr + d8), s1 = *(const float4*)(sr + d8 + 4);
  float4 s2 = *(const float4*)(sr + d8 + 64), s3 = *(const float4*)(sr + d8 + 68);
  float cl[8] = {c0.x, c0.y, c0.z, c0.w, c1.x, c1.y, c1.z, c1.w};
  float ch[8] = {c2.x, c2.y, c2.z, c2.w, c3.x, c3.y, c3.z, c3.w};
  float sl[8] = {s0.x, s0.y, s0.z, s0.w, s1.x, s1.y, s1.z, s1.w};
  float sh[8] = {s2.x, s2.y, s2.z, s2.w, s3.x, s3.y, s3.z, s3.w};
  bf16x8 olo, ohi;
#pragma unroll
  for (int i = 0; i < 8; ++i) {
    float q1 = bf2f((unsigned short)qlo[i]);
    float q2 = bf2f((unsigned short)qhi[i]);
    olo[i] = (short)f2bf((q1 * cl[i] - q2 * sl[i]) * scale);
    ohi[i] = (short)f2bf((q2 * ch[i] + q1 * sh[i]) * scale);
  }
  *(bf16x8*)(q) = olo;
  *(bf16x8*)(q + 64) = ohi;
}

// ---------------- Flash attention v9: 64 q/wave (2 sets), QBLK=512 ----------------
// Each LDS K/V fragment read ONCE feeds TWO MFMAs (set A: rows q0w+l31, set B: +32).
// Halves per-CU LDS-read traffic (the measured bottleneck). 256 blocks = 1/CU.
__global__ __launch_bounds__(512) void flash_attn(const unsigned short* __restrict__ Qb,
                                                  const unsigned short* __restrict__ Kb,
                                                  const unsigned short* __restrict__ Vb,
                                                  unsigned short* __restrict__ Ob) {
  __shared__ unsigned short KsArr[2 * 8192];   // [buf][key*128 + (c ^ ((key&15)<<3))]
  __shared__ unsigned int VtArr[2 * 4608];     // [buf][d*36 + 4*((kp>>2)^((d>>3)&7)) + (kp&3)]

  const int tid = threadIdx.x, wid = tid >> 6, lane = tid & 63;
  const int l31 = lane & 31, hi5 = lane >> 5;

  // XCD bh-grouping: 256 blocks; XCD r gets bh {r, r+8, ...} with all 4 q-blocks.
  const int L = blockIdx.y * 8 + blockIdx.x;     // grid (8, 32)
  const int bh = ((L >> 5) << 3) | (L & 7);
  const int qt = (L >> 3) & 3;
  const int b = bh >> 4, h = bh & 15;
  const long rowbase = (long)b * NL;
  const int colbase = h * NDH;
  const long q0 = (long)qt * 512 + wid * 64;     // wave's 64 q-rows: [q0, q0+64)

  // Q fragments for both sets: B-operand, col = q, k = kc*16 + hi5*8 + j
  bf16x8 qfA[8], qfB[8];
  {
    const unsigned short* qpA = Qb + (rowbase + q0 + l31) * (long)ND + colbase + hi5 * 8;
    const unsigned short* qpB = qpA + 32 * (long)ND;
#pragma unroll
    for (int kc = 0; kc < 8; ++kc) {
      qfA[kc] = *(const bf16x8*)(qpA + kc * 16);
      qfB[kc] = *(const bf16x8*)(qpB + kc * 16);
    }
  }

  f32x16 oaccA[4], oaccB[4];
#pragma unroll
  for (int db = 0; db < 4; ++db)
#pragma unroll
    for (int i = 0; i < 16; ++i) { oaccA[db][i] = 0.f; oaccB[db][i] = 0.f; }
  float mrunA = -1e30f, lrunA = 0.f;
  float mrunB = -1e30f, lrunB = 0.f;

  // staging: thread covers keys (2kp, 2kp+1) at d-cols c8..c8+7
  const int kp = tid >> 4;                 // 0..31
  const int c8 = (tid & 15) * 8;
  bf16x8 kreg[2], vreg[2];

#define LOAD_KV(kt_) do {                                                          \
    _Pragma("unroll") for (int j = 0; j < 2; ++j) {                                \
      const long grow = (rowbase + (kt_) * 64 + 2 * kp + j) * (long)ND + colbase + c8; \
      kreg[j] = *(const bf16x8*)(Kb + grow);                                       \
      vreg[j] = *(const bf16x8*)(Vb + grow);                                       \
    } } while (0)

#define WRITE_KV(bi) do {                                                          \
    _Pragma("unroll") for (int j = 0; j < 2; ++j) {                                \
      int row_ = 2 * kp + j;                                                       \
      *(bf16x8*)(KsArr + (bi) * 8192 + row_ * 128 + (c8 ^ ((row_ & 15) << 3))) = kreg[j]; \
    }                                                                              \
    _Pragma("unroll") for (int i = 0; i < 8; ++i) {                                \
      int d_ = c8 + i;                                                             \
      VtArr[(bi) * 4608 + d_ * 36 + 4 * ((kp >> 2) ^ ((d_ >> 3) & 7)) + (kp & 3)] = \
          (unsigned int)(unsigned short)vreg[0][i] |                               \
          ((unsigned int)(unsigned short)vreg[1][i] << 16);                        \
    } } while (0)

  // softmax for one set (macro over sacc/oacc/mrun/lrun)
#define SOFTMAX_PACK(sacc, oacc, mrun, lrun, pa) do {                              \
    float mxa[8];                                                                  \
    _Pragma("unroll") for (int i = 0; i < 8; ++i)                                  \
      mxa[i] = fmaxf(fmaxf(sacc[0][i], sacc[0][i + 8]),                            \
                     fmaxf(sacc[1][i], sacc[1][i + 8]));                           \
    float mx = fmaxf(fmaxf(fmaxf(mxa[0], mxa[1]), fmaxf(mxa[2], mxa[3])),          \
                     fmaxf(fmaxf(mxa[4], mxa[5]), fmaxf(mxa[6], mxa[7])));         \
    mx = fmaxf(mx, __shfl_xor(mx, 32));                                            \
    if (!__all(mx - mrun <= 8.f)) {                                                \
      float mnew = fmaxf(mrun, mx);                                                \
      float corr = exp2_fast(mrun - mnew);                                         \
      mrun = mnew;                                                                 \
      lrun *= corr;                                                                \
      _Pragma("unroll") for (int db = 0; db < 4; ++db)                             \
        _Pragma("unroll") for (int i = 0; i < 16; ++i) oacc[db][i] *= corr;        \
    }                                                                              \
    float s4[4] = {0.f, 0.f, 0.f, 0.f};                                            \
    _Pragma("unroll") for (int nb = 0; nb < 2; ++nb)                               \
      _Pragma("unroll") for (int r = 0; r < 16; ++r) {                             \
        float e = exp2_fast(sacc[nb][r] - mrun);                                   \
        sacc[nb][r] = e;                                                           \
        s4[r & 3] += e;                                                            \
      }                                                                            \
    float s = (s4[0] + s4[1]) + (s4[2] + s4[3]);                                   \
    s += __shfl_xor(s, 32);                                                        \
    lrun += s;                                                                     \
    _Pragma("unroll") for (int nb = 0; nb < 2; ++nb) {                             \
      unsigned int x1 = cvtpk(sacc[nb][0], sacc[nb][1]);                           \
      unsigned int x2 = cvtpk(sacc[nb][2], sacc[nb][3]);                           \
      unsigned int y1 = cvtpk(sacc[nb][4], sacc[nb][5]);                           \
      unsigned int y2 = cvtpk(sacc[nb][6], sacc[nb][7]);                           \
      unsigned int z1 = cvtpk(sacc[nb][8], sacc[nb][9]);                           \
      unsigned int z2 = cvtpk(sacc[nb][10], sacc[nb][11]);                         \
      unsigned int w1 = cvtpk(sacc[nb][12], sacc[nb][13]);                         \
      unsigned int w2 = cvtpk(sacc[nb][14], sacc[nb][15]);                         \
      permswap(x1, y1);                                                            \
      permswap(x2, y2);                                                            \
      permswap(z1, w1);                                                            \
      permswap(z2, w2);                                                            \
      pa[nb][0].u[0] = x1; pa[nb][0].u[1] = x2; pa[nb][0].u[2] = y1; pa[nb][0].u[3] = y2; \
      pa[nb][1].u[0] = z1; pa[nb][1].u[1] = z2; pa[nb][1].u[2] = w1; pa[nb][1].u[3] = w2; \
    } } while (0)

  // prologue: tile 0 -> buf 0; then prefetch tile 1
  LOAD_KV(0);
  WRITE_KV(0);
  __syncthreads();
  LOAD_KV(1);

  const int NT = NL / 64;
  for (int kt = 0; kt < NT; ++kt) {
    const int bf = kt & 1;
    const unsigned short* Ksb = KsArr + bf * 8192;
    const unsigned int* Vtb = VtArr + bf * 4608;

    // 1. S^T = mfma32(K, Q) both sets; each kf read feeds 2 MFMA
    f32x16 saccA[2], saccB[2];
    __builtin_amdgcn_s_setprio(1);
#pragma unroll
    for (int nb = 0; nb < 2; ++nb) {
#pragma unroll
      for (int i = 0; i < 16; ++i) { saccA[nb][i] = 0.f; saccB[nb][i] = 0.f; }
#pragma unroll
      for (int kc = 0; kc < 8; ++kc) {
        int row = nb * 32 + l31;
        bf16x8 kf = *(const bf16x8*)(Ksb + row * 128 + ((kc * 16 + hi5 * 8) ^ ((row & 15) << 3)));
        saccA[nb] = __builtin_amdgcn_mfma_f32_32x32x16_bf16(kf, qfA[kc], saccA[nb], 0, 0, 0);
        saccB[nb] = __builtin_amdgcn_mfma_f32_32x32x16_bf16(kf, qfB[kc], saccB[nb], 0, 0, 0);
      }
    }
    __builtin_amdgcn_s_setprio(0);

    // 2. stage tile kt+1 regs -> other buffer (overlaps softmax below)
    if (kt + 1 < NT) WRITE_KV(bf ^ 1);
    // 3. prefetch tile kt+2 -> regs
    if (kt + 2 < NT) LOAD_KV(kt + 2);

    // 4. softmax + P-pack per set (T12/T13)
    union { unsigned int u[4]; bf16x8 v; } paA[2][2], paB[2][2];
    SOFTMAX_PACK(saccA, oaccA, mrunA, lrunA, paA);
    SOFTMAX_PACK(saccB, oaccB, mrunB, lrunB, paB);

    // 5. PV both sets; each vf read feeds 2 MFMA
    __builtin_amdgcn_s_setprio(1);
#pragma unroll
    for (int db = 0; db < 4; ++db) {
      int d = db * 32 + l31;
      int dsw = (d >> 3) & 7;
#pragma unroll
      for (int nb = 0; nb < 2; ++nb)
#pragma unroll
        for (int ks = 0; ks < 2; ++ks) {
          int g = nb * 4 + ks * 2 + hi5;
          bf16x8 vf = *(const bf16x8*)(Vtb + d * 36 + 4 * (g ^ dsw));
          oaccA[db] = __builtin_amdgcn_mfma_f32_32x32x16_bf16(vf, paA[nb][ks].v, oaccA[db], 0, 0, 0);
          oaccB[db] = __builtin_amdgcn_mfma_f32_32x32x16_bf16(vf, paB[nb][ks].v, oaccB[db], 0, 0, 0);
        }
    }
    __builtin_amdgcn_s_setprio(0);
    __syncthreads();   // buf bf free for overwrite; buf bf^1 writes visible
  }
#undef LOAD_KV
#undef WRITE_KV
#undef SOFTMAX_PACK

  // ---------- epilogue: O^T -> O via per-wave LDS scratch (reuse VtArr), coalesced ----------
  unsigned short* scr = (unsigned short*)VtArr + wid * 2304;   // 32 rows x 72
#pragma unroll
  for (int set = 0; set < 2; ++set) {
    const f32x16* oacc = set ? oaccB : oaccA;
    float rinv = 1.0f / (set ? lrunB : lrunA);
    long qset = q0 + set * 32;
#pragma unroll
    for (int c = 0; c < 2; ++c) {          // d-chunks [0,64) and [64,128)
      asm volatile("s_waitcnt lgkmcnt(0)" ::: "memory");
      __builtin_amdgcn_sched_barrier(0);
#pragma unroll
      for (int dbh = 0; dbh < 2; ++dbh) {
        int db = 2 * c + dbh;
#pragma unroll
        for (int t = 0; t < 8; ++t) {
          int d_lo = dbh * 32 + ((2 * t) & 3) + 8 * (t >> 1) + 4 * hi5;
          unsigned int pv = cvtpk(oacc[db][2 * t] * rinv, oacc[db][2 * t + 1] * rinv);
          *(unsigned int*)(scr + l31 * 72 + d_lo) = pv;
        }
      }
      asm volatile("s_waitcnt lgkmcnt(0)" ::: "memory");
      __builtin_amdgcn_sched_barrier(0);
#pragma unroll
      for (int j = 0; j < 4; ++j) {
        int row = j * 8 + (lane >> 3);
        bf16x8 ov = *(const bf16x8*)(scr + row * 72 + (lane & 7) * 8);
        *(bf16x8*)(Ob + (rowbase + qset + row) * (long)ND + colbase + c * 64 + (lane & 7) * 8) = ov;
      }
    }
  }
}

// ---------------- launch ----------------
extern "C" void kernel_launch(void* const* d_in, const int* in_sizes, int n_in,
                              void* d_out, int out_size, void* d_ws, size_t ws_size,
                              hipStream_t stream) {
  const float* x = (const float*)d_in[0];
  const float* rope_cos = (const float*)d_in[1];
  const float* rope_sin = (const float*)d_in[2];
  const float* W_q = (const float*)d_in[3];
  const float* W_dkv = (const float*)d_in[4];
  const float* W_uk = (const float*)d_in[5];
  const float* W_uv = (const float*)d_in[6];
  const float* W_o = (const float*)d_in[7];
  float* out = (float*)d_out;

  char* p = (char*)d_ws;
  unsigned short* xb = (unsigned short*)p;    p += (size_t)NROWS * ND * 2;
  unsigned short* Wqb = (unsigned short*)p;   p += (size_t)ND * ND * 2;
  unsigned short* Wdkvb = (unsigned short*)p; p += (size_t)NDC * ND * 2;
  unsigned short* Wukb = (unsigned short*)p;  p += (size_t)ND * NDC * 2;
  unsigned short* Wuvb = (unsigned short*)p;  p += (size_t)ND * NDC * 2;
  unsigned short* Wob = (unsigned short*)p;   p += (size_t)ND * ND * 2;
  unsigned short* Qb = (unsigned short*)p;    p += (size_t)NROWS * ND * 2;
  unsigned short* ckv = (unsigned short*)p;   p += (size_t)NROWS * NDC * 2;
  unsigned short* Kbf = (unsigned short*)p;   p += (size_t)NROWS * ND * 2;
  unsigned short* Vbf = (unsigned short*)p;   p += (size_t)NROWS * ND * 2;
  unsigned short* AO = (unsigned short*)p;    p += (size_t)NROWS * ND * 2;

  // fp32 -> bf16
  {
    struct { const float* s; unsigned short* d; long n; } cv[6] = {
      {x, xb, (long)NROWS * ND},
      {W_q, Wqb, (long)ND * ND},
      {W_dkv, Wdkvb, (long)NDC * ND},
      {W_uk, Wukb, (long)ND * NDC},
      {W_uv, Wuvb, (long)ND * NDC},
      {W_o, Wob, (long)ND * ND},
    };
    for (int i = 0; i < 6; ++i) {
      int n4 = (int)(cv[i].n / 4);
      int blocks = (n4 + 255) / 256;
      if (blocks > 2048) blocks = 2048;
      cvt_kernel<<<blocks, 256, 0, stream>>>((const float4*)cv[i].s, (ushort4*)cv[i].d, n4);
    }
  }

  // projections: 256^2 8-phase for nwg=256 shapes; 128^2 for dkv (N=512)
  gemm_nt256<0><<<dim3(ND / 256, NROWS / 256), 512, 0, stream>>>(xb, Wqb, Qb, NROWS, ND, ND);
  gemm_nt<0><<<dim3(NDC / 128, NROWS / 128), 256, 0, stream>>>(xb, Wdkvb, ckv, NROWS, NDC, ND);
  gemm_nt256<0><<<dim3(ND / 256, NROWS / 256), 512, 0, stream>>>(ckv, Wukb, Kbf, NROWS, ND, NDC);
  gemm_nt256<0><<<dim3(ND / 256, NROWS / 256), 512, 0, stream>>>(ckv, Wuvb, Vbf, NROWS, ND, NDC);

  // RoPE: Q gets 1/sqrt(DH) * log2(e) (softmax uses exp2); K gets 1.0
  const float scale_q = 0.08838834764831845f * 1.4426950408889634f;
  rope_kernel<<<NROWS, 128, 0, stream>>>(Qb, rope_cos, rope_sin, scale_q);
  rope_kernel<<<NROWS, 128, 0, stream>>>(Kbf, rope_cos, rope_sin, 1.0f);

  // attention: 256 blocks (QBLK=512, 64 q/wave)
  flash_attn<<<dim3(8, 32), 512, 0, stream>>>(Qb, Kbf, Vbf, AO);

  // output projection (fp32 out)
  gemm_nt256<1><<<dim3(ND / 256, NROWS / 256), 512, 0, stream>>>(AO, Wob, out, NROWS, ND, ND);
}

// Round 11
// 492.692 us; speedup vs baseline: 1.4254x; 1.4254x over previous
//
#include <hip/hip_runtime.h>
#include <math.h>

typedef __attribute__((ext_vector_type(8))) short bf16x8;
typedef __attribute__((ext_vector_type(4))) float f32x4;
typedef __attribute__((ext_vector_type(16))) float f32x16;

#define NB 4
#define NL 2048
#define ND 2048
#define NH 16
#define NDH 128
#define NDC 512
#define NROWS (NB*NL)

__device__ __forceinline__ unsigned short f2bf(float f) {
  unsigned int u = __float_as_uint(f);
  u += 0x7fffu + ((u >> 16) & 1u);
  return (unsigned short)(u >> 16);
}
__device__ __forceinline__ float bf2f(unsigned short h) {
  return __uint_as_float(((unsigned int)h) << 16);
}
__device__ __forceinline__ unsigned int cvtpk(float lo, float hi) {
  unsigned int r;
  asm("v_cvt_pk_bf16_f32 %0, %1, %2" : "=v"(r) : "v"(lo), "v"(hi));
  return r;
}
// v_permlane32_swap_b32: a.lanes[32:63] <-> b.lanes[0:31]
__device__ __forceinline__ void permswap(unsigned int &a, unsigned int &b) {
  asm("v_permlane32_swap_b32 %0, %1" : "+v"(a), "+v"(b));
}
__device__ __forceinline__ float exp2_fast(float x) {
  float r; asm("v_exp_f32 %0, %1" : "=v"(r) : "v"(x)); return r;
}

__device__ __forceinline__ void gld16(const void* g, void* l) {
  __builtin_amdgcn_global_load_lds((const __attribute__((address_space(1))) void*)g,
                                   (__attribute__((address_space(3))) void*)l, 16, 0, 0);
}

// ---------------- fp32 -> bf16 convert ----------------
__global__ void cvt_kernel(const float4* __restrict__ in, ushort4* __restrict__ out, int n4) {
  int stride = gridDim.x * blockDim.x;
  for (int i = blockIdx.x * blockDim.x + threadIdx.x; i < n4; i += stride) {
    float4 v = in[i];
    ushort4 o;
    o.x = f2bf(v.x); o.y = f2bf(v.y); o.z = f2bf(v.z); o.w = f2bf(v.w);
    out[i] = o;
  }
}

// ---------------- 128^2 NT GEMM (kept for N=512 shapes) ----------------
template<int OUT_F32>
__global__ __launch_bounds__(256) void gemm_nt(const unsigned short* __restrict__ A,
                                               const unsigned short* __restrict__ Bm,
                                               void* __restrict__ Cv,
                                               int M, int N, int K) {
  __shared__ unsigned short As[128 * 32];
  __shared__ unsigned short Bs[128 * 32];
  const int tid = threadIdx.x;
  const int wid = tid >> 6;
  const int lane = tid & 63;
  const int wr = wid >> 1, wc = wid & 1;
  const long bm = blockIdx.y, bn = blockIdx.x;
  const int r15 = lane & 15;
  const int koff = (lane >> 4) * 8;
  const int srow = lane >> 2;
  const int scol = (lane & 3) * 8;

  f32x4 acc[4][4];
#pragma unroll
  for (int m = 0; m < 4; ++m)
#pragma unroll
    for (int n = 0; n < 4; ++n) acc[m][n] = (f32x4){0.f, 0.f, 0.f, 0.f};

  const unsigned short* Ablk = A + (bm * 128 + wid * 16 + srow) * (long)K + scol;
  const unsigned short* Bblk = Bm + (bn * 128 + wid * 16 + srow) * (long)K + scol;
  unsigned short* AsW = As + wid * 16 * 32;
  unsigned short* BsW = Bs + wid * 16 * 32;

  for (int kk = 0; kk < K; kk += 32) {
    __syncthreads();
#pragma unroll
    for (int j = 0; j < 2; ++j) {
      gld16(Ablk + (long)j * 64 * K + kk, AsW + j * 64 * 32);
      gld16(Bblk + (long)j * 64 * K + kk, BsW + j * 64 * 32);
    }
    __syncthreads();
    bf16x8 af[4], bfr[4];
#pragma unroll
    for (int m = 0; m < 4; ++m)
      af[m] = *(const bf16x8*)(As + (wr * 64 + m * 16 + r15) * 32 + koff);
#pragma unroll
    for (int n = 0; n < 4; ++n)
      bfr[n] = *(const bf16x8*)(Bs + (wc * 64 + n * 16 + r15) * 32 + koff);
#pragma unroll
    for (int m = 0; m < 4; ++m)
#pragma unroll
      for (int n = 0; n < 4; ++n)
        acc[m][n] = __builtin_amdgcn_mfma_f32_16x16x32_bf16(af[m], bfr[n], acc[m][n], 0, 0, 0);
  }

  const int rr = (lane >> 4) * 4;
#pragma unroll
  for (int m = 0; m < 4; ++m) {
#pragma unroll
    for (int n = 0; n < 4; ++n) {
      long row0 = bm * 128 + wr * 64 + m * 16 + rr;
      long col = bn * 128 + wc * 64 + n * 16 + r15;
#pragma unroll
      for (int r = 0; r < 4; ++r) {
        float v = acc[m][n][r];
        if (OUT_F32) ((float*)Cv)[(row0 + r) * (long)N + col] = v;
        else ((unsigned short*)Cv)[(row0 + r) * (long)N + col] = f2bf(v);
      }
    }
  }
}

// ---------------- 256^2 8-phase NT GEMM (T1+T2+T3+T4+T5) ----------------
template<int OUT_F32>
__global__ __launch_bounds__(512) void gemm_nt256(const unsigned short* __restrict__ A,
                                                  const unsigned short* __restrict__ Bm,
                                                  void* __restrict__ Cv,
                                                  int M, int N, int K) {
  __shared__ unsigned short lds[2][2][16384];   // [buf][0=A,1=B][256 rows x 64 cols]
  const int tid = threadIdx.x;
  const int wid = tid >> 6, lane = tid & 63;
  const int wm = wid >> 2, wn = wid & 3;
  const int r15 = lane & 15, khi = lane >> 4;

  const int gx = gridDim.x;
  int bid = blockIdx.y * gx + blockIdx.x;
  int cpx = (gx * gridDim.y) >> 3;
  int swz = (bid & 7) * cpx + (bid >> 3);
  const long bm = swz / gx, bn = swz % gx;

  const int c0 = tid, c1 = 512 + tid;
  const int r0 = c0 >> 3, r1 = c1 >> 3;
  const int cs0 = ((c0 & 7) ^ (r0 & 7)) * 8;
  const int cs1 = ((c1 & 7) ^ (r1 & 7)) * 8;
  const unsigned short* srcA = A + (bm * 256) * (long)K;
  const unsigned short* srcB = Bm + (bn * 256) * (long)K;

#define STAGE256(mat, h, kb, bufi) do {                                              \
    const unsigned short* s_ = (mat) ? srcB : srcA;                                  \
    gld16(s_ + ((h) * 128 + r0) * (long)K + (kb) + cs0,                              \
          &lds[bufi][mat][(h) * 8192 + wid * 512]);                                  \
    gld16(s_ + ((h) * 128 + r1) * (long)K + (kb) + cs1,                              \
          &lds[bufi][mat][(h) * 8192 + 4096 + wid * 512]);                           \
  } while (0)

  f32x4 acc[8][4];
#pragma unroll
  for (int m = 0; m < 8; ++m)
#pragma unroll
    for (int n = 0; n < 4; ++n) acc[m][n] = (f32x4){0.f, 0.f, 0.f, 0.f};

  const int NT = K >> 6;
  STAGE256(0, 0, 0, 0); STAGE256(0, 1, 0, 0);
  STAGE256(1, 0, 0, 0); STAGE256(1, 1, 0, 0);

  for (int t = 0; t < NT; ++t) {
    const int buf = t & 1, nbuf = buf ^ 1;
    const int kb1 = (t + 1) << 6;
    const bool pf = (t + 1 < NT);
    __builtin_amdgcn_s_barrier();
    if (pf) {
      STAGE256(0, 0, kb1, nbuf);
      asm volatile("s_waitcnt vmcnt(2)" ::: "memory");
    } else {
      asm volatile("s_waitcnt vmcnt(0)" ::: "memory");
    }
    __builtin_amdgcn_s_barrier();

    bf16x8 bfr[4][2];
#pragma unroll
    for (int n = 0; n < 4; ++n)
#pragma unroll
      for (int kk = 0; kk < 2; ++kk) {
        int rb = wn * 64 + n * 16 + r15;
        bfr[n][kk] = *(const bf16x8*)&lds[buf][1][rb * 64 + (((kk * 4 + khi) ^ (rb & 7)) * 8)];
      }
#pragma unroll
    for (int mb = 0; mb < 4; ++mb) {
      if (mb != 0) {
        __builtin_amdgcn_s_barrier();
        if (pf) {
          if (mb == 1) STAGE256(0, 1, kb1, nbuf);
          else if (mb == 2) STAGE256(1, 0, kb1, nbuf);
          else STAGE256(1, 1, kb1, nbuf);
        }
      }
      bf16x8 af[2][2];
#pragma unroll
      for (int m2 = 0; m2 < 2; ++m2)
#pragma unroll
        for (int kk = 0; kk < 2; ++kk) {
          int ra = wm * 128 + mb * 32 + m2 * 16 + r15;
          af[m2][kk] = *(const bf16x8*)&lds[buf][0][ra * 64 + (((kk * 4 + khi) ^ (ra & 7)) * 8)];
        }
      asm volatile("s_waitcnt lgkmcnt(0)" ::: "memory");
      __builtin_amdgcn_sched_barrier(0);
      __builtin_amdgcn_s_setprio(1);
#pragma unroll
      for (int m2 = 0; m2 < 2; ++m2)
#pragma unroll
        for (int n = 0; n < 4; ++n)
#pragma unroll
          for (int kk = 0; kk < 2; ++kk)
            acc[mb * 2 + m2][n] = __builtin_amdgcn_mfma_f32_16x16x32_bf16(
                af[m2][kk], bfr[n][kk], acc[mb * 2 + m2][n], 0, 0, 0);
      __builtin_amdgcn_s_setprio(0);
    }
  }
#undef STAGE256

#pragma unroll
  for (int mi = 0; mi < 8; ++mi) {
#pragma unroll
    for (int n = 0; n < 4; ++n) {
      long row0 = bm * 256 + wm * 128 + mi * 16 + khi * 4;
      long col = bn * 256 + wn * 64 + n * 16 + r15;
#pragma unroll
      for (int r = 0; r < 4; ++r) {
        float v = acc[mi][n][r];
        if (OUT_F32) ((float*)Cv)[(row0 + r) * (long)N + col] = v;
        else ((unsigned short*)Cv)[(row0 + r) * (long)N + col] = f2bf(v);
      }
    }
  }
}

// ---------------- RoPE in-place (vectorized: 8 pairs/thread, bf16x8 loads) ----------------
__global__ void rope_kernel(unsigned short* __restrict__ Qb, const float* __restrict__ cosb,
                            const float* __restrict__ sinb, float scale) {
  const long row = blockIdx.x;
  const int p = threadIdx.x;            // 0..127
  const int h = p >> 3, d8 = (p & 7) * 8;
  const float* cr = cosb + row * NDH;
  const float* sr = sinb + row * NDH;
  unsigned short* q = Qb + row * (long)ND + h * 128 + d8;

  bf16x8 qlo = *(const bf16x8*)(q);
  bf16x8 qhi = *(const bf16x8*)(q + 64);
  float4 c0 = *(const float4*)(cr + d8), c1 = *(const float4*)(cr + d8 + 4);
  float4 c2 = *(const float4*)(cr + d8 + 64), c3 = *(const float4*)(cr + d8 + 68);
  float4 s0 = *(const float4*)(sr + d8), s1 = *(const float4*)(sr + d8 + 4);
  float4 s2 = *(const float4*)(sr + d8 + 64), s3 = *(const float4*)(sr + d8 + 68);
  float cl[8] = {c0.x, c0.y, c0.z, c0.w, c1.x, c1.y, c1.z, c1.w};
  float ch[8] = {c2.x, c2.y, c2.z, c2.w, c3.x, c3.y, c3.z, c3.w};
  float sl[8] = {s0.x, s0.y, s0.z, s0.w, s1.x, s1.y, s1.z, s1.w};
  float sh[8] = {s2.x, s2.y, s2.z, s2.w, s3.x, s3.y, s3.z, s3.w};
  bf16x8 olo, ohi;
#pragma unroll
  for (int i = 0; i < 8; ++i) {
    float q1 = bf2f((unsigned short)qlo[i]);
    float q2 = bf2f((unsigned short)qhi[i]);
    olo[i] = (short)f2bf((q1 * cl[i] - q2 * sl[i]) * scale);
    ohi[i] = (short)f2bf((q2 * ch[i] + q1 * sh[i]) * scale);
  }
  *(bf16x8*)(q) = olo;
  *(bf16x8*)(q + 64) = ohi;
}

// ---------------- Flash attention v10: 64 q/wave, 4 waves/block (256 thr) ----------------
// v9's reuse (each LDS K/V read feeds 2 MFMAs) re-blocked so ~300 regs/wave FITS:
// __launch_bounds__(256,1) -> up to ~512 regs/wave, no spill (round-10 failure mode).
// QBLK=256 (4 waves x 64 q), grid 512 blocks, XCD bh-grouping as v8.
__global__ __launch_bounds__(256, 1) void flash_attn(const unsigned short* __restrict__ Qb,
                                                     const unsigned short* __restrict__ Kb,
                                                     const unsigned short* __restrict__ Vb,
                                                     unsigned short* __restrict__ Ob) {
  __shared__ unsigned short KsArr[2 * 8192];   // [buf][key*128 + (c ^ ((key&15)<<3))]
  __shared__ unsigned int VtArr[2 * 4608];     // [buf][d*36 + 4*((kp2>>2)^((d>>3)&7)) + (kp2&3)]

  const int tid = threadIdx.x, wid = tid >> 6, lane = tid & 63;
  const int l31 = lane & 31, hi5 = lane >> 5;

  // XCD bh-grouping: linear L -> bh = (L>>6)*8 + (L&7), qt = (L>>3)&7
  const int L = blockIdx.y * 8 + blockIdx.x;   // grid (8, 64)
  const int bh = ((L >> 6) << 3) | (L & 7);
  const int qt = (L >> 3) & 7;
  const int b = bh >> 4, h = bh & 15;
  const long rowbase = (long)b * NL;
  const int colbase = h * NDH;
  const long q0 = (long)qt * 256 + wid * 64;   // wave's 64 q-rows

  // Q fragments for both sets: B-operand, col = q, k = kc*16 + hi5*8 + j
  bf16x8 qfA[8], qfB[8];
  {
    const unsigned short* qpA = Qb + (rowbase + q0 + l31) * (long)ND + colbase + hi5 * 8;
    const unsigned short* qpB = qpA + 32 * (long)ND;
#pragma unroll
    for (int kc = 0; kc < 8; ++kc) {
      qfA[kc] = *(const bf16x8*)(qpA + kc * 16);
      qfB[kc] = *(const bf16x8*)(qpB + kc * 16);
    }
  }

  f32x16 oaccA[4], oaccB[4];
#pragma unroll
  for (int db = 0; db < 4; ++db)
#pragma unroll
    for (int i = 0; i < 16; ++i) { oaccA[db][i] = 0.f; oaccB[db][i] = 0.f; }
  float mrunA = -1e30f, lrunA = 0.f;
  float mrunB = -1e30f, lrunB = 0.f;

  // staging: 256 threads cover 64 keys x 128 d; thread covers keys 4kp..4kp+3 at d-cols c8..c8+7
  const int kp = tid >> 4;                 // 0..15
  const int c8 = (tid & 15) * 8;
  bf16x8 kreg[4], vreg[4];

#define LOAD_KV(kt_) do {                                                          \
    _Pragma("unroll") for (int j = 0; j < 4; ++j) {                                \
      const long grow = (rowbase + (kt_) * 64 + 4 * kp + j) * (long)ND + colbase + c8; \
      kreg[j] = *(const bf16x8*)(Kb + grow);                                       \
      vreg[j] = *(const bf16x8*)(Vb + grow);                                       \
    } } while (0)

#define WRITE_KV(bi) do {                                                          \
    _Pragma("unroll") for (int j = 0; j < 4; ++j) {                                \
      int row_ = 4 * kp + j;                                                       \
      *(bf16x8*)(KsArr + (bi) * 8192 + row_ * 128 + (c8 ^ ((row_ & 15) << 3))) = kreg[j]; \
    }                                                                              \
    _Pragma("unroll") for (int i = 0; i < 8; ++i) {                                \
      int d_ = c8 + i;                                                             \
      int dsw_ = (d_ >> 3) & 7;                                                    \
      _Pragma("unroll") for (int pr = 0; pr < 2; ++pr) {                           \
        int kp2 = 2 * kp + pr;                                                     \
        VtArr[(bi) * 4608 + d_ * 36 + 4 * ((kp2 >> 2) ^ dsw_) + (kp2 & 3)] =       \
            (unsigned int)(unsigned short)vreg[2 * pr][i] |                        \
            ((unsigned int)(unsigned short)vreg[2 * pr + 1][i] << 16);             \
      }                                                                            \
    } } while (0)

  // softmax + pack for one set (T12/T13)
#define SOFTMAX_PACK(sacc, oacc, mrun, lrun, pa) do {                              \
    float mxa[8];                                                                  \
    _Pragma("unroll") for (int i = 0; i < 8; ++i)                                  \
      mxa[i] = fmaxf(fmaxf(sacc[0][i], sacc[0][i + 8]),                            \
                     fmaxf(sacc[1][i], sacc[1][i + 8]));                           \
    float mx = fmaxf(fmaxf(fmaxf(mxa[0], mxa[1]), fmaxf(mxa[2], mxa[3])),          \
                     fmaxf(fmaxf(mxa[4], mxa[5]), fmaxf(mxa[6], mxa[7])));         \
    mx = fmaxf(mx, __shfl_xor(mx, 32));                                            \
    if (!__all(mx - mrun <= 8.f)) {                                                \
      float mnew = fmaxf(mrun, mx);                                                \
      float corr = exp2_fast(mrun - mnew);                                         \
      mrun = mnew;                                                                 \
      lrun *= corr;                                                                \
      _Pragma("unroll") for (int db = 0; db < 4; ++db)                             \
        _Pragma("unroll") for (int i = 0; i < 16; ++i) oacc[db][i] *= corr;        \
    }                                                                              \
    float s4[4] = {0.f, 0.f, 0.f, 0.f};                                            \
    _Pragma("unroll") for (int nb = 0; nb < 2; ++nb)                               \
      _Pragma("unroll") for (int r = 0; r < 16; ++r) {                             \
        float e = exp2_fast(sacc[nb][r] - mrun);                                   \
        sacc[nb][r] = e;                                                           \
        s4[r & 3] += e;                                                            \
      }                                                                            \
    float s = (s4[0] + s4[1]) + (s4[2] + s4[3]);                                   \
    s += __shfl_xor(s, 32);                                                        \
    lrun += s;                                                                     \
    _Pragma("unroll") for (int nb = 0; nb < 2; ++nb) {                             \
      unsigned int x1 = cvtpk(sacc[nb][0], sacc[nb][1]);                           \
      unsigned int x2 = cvtpk(sacc[nb][2], sacc[nb][3]);                           \
      unsigned int y1 = cvtpk(sacc[nb][4], sacc[nb][5]);                           \
      unsigned int y2 = cvtpk(sacc[nb][6], sacc[nb][7]);                           \
      unsigned int z1 = cvtpk(sacc[nb][8], sacc[nb][9]);                           \
      unsigned int z2 = cvtpk(sacc[nb][10], sacc[nb][11]);                         \
      unsigned int w1 = cvtpk(sacc[nb][12], sacc[nb][13]);                         \
      unsigned int w2 = cvtpk(sacc[nb][14], sacc[nb][15]);                         \
      permswap(x1, y1);                                                            \
      permswap(x2, y2);                                                            \
      permswap(z1, w1);                                                            \
      permswap(z2, w2);                                                            \
      pa[nb][0].u[0] = x1; pa[nb][0].u[1] = x2; pa[nb][0].u[2] = y1; pa[nb][0].u[3] = y2; \
      pa[nb][1].u[0] = z1; pa[nb][1].u[1] = z2; pa[nb][1].u[2] = w1; pa[nb][1].u[3] = w2; \
    } } while (0)

  // prologue: tile 0 -> buf 0; then prefetch tile 1
  LOAD_KV(0);
  WRITE_KV(0);
  __syncthreads();
  LOAD_KV(1);

  const int NT = NL / 64;
  for (int kt = 0; kt < NT; ++kt) {
    const int bf = kt & 1;
    const unsigned short* Ksb = KsArr + bf * 8192;
    const unsigned int* Vtb = VtArr + bf * 4608;

    // 1. S^T = mfma32(K, Q) both sets; each kf read feeds 2 MFMA
    f32x16 saccA[2], saccB[2];
    __builtin_amdgcn_s_setprio(1);
#pragma unroll
    for (int nb = 0; nb < 2; ++nb) {
#pragma unroll
      for (int i = 0; i < 16; ++i) { saccA[nb][i] = 0.f; saccB[nb][i] = 0.f; }
#pragma unroll
      for (int kc = 0; kc < 8; ++kc) {
        int row = nb * 32 + l31;
        bf16x8 kf = *(const bf16x8*)(Ksb + row * 128 + ((kc * 16 + hi5 * 8) ^ ((row & 15) << 3)));
        saccA[nb] = __builtin_amdgcn_mfma_f32_32x32x16_bf16(kf, qfA[kc], saccA[nb], 0, 0, 0);
        saccB[nb] = __builtin_amdgcn_mfma_f32_32x32x16_bf16(kf, qfB[kc], saccB[nb], 0, 0, 0);
      }
    }
    __builtin_amdgcn_s_setprio(0);

    // 2. stage tile kt+1 regs -> other buffer (overlaps softmax below)
    if (kt + 1 < NT) WRITE_KV(bf ^ 1);
    // 3. prefetch tile kt+2 -> regs
    if (kt + 2 < NT) LOAD_KV(kt + 2);

    // 4. softmax + P-pack per set (T12/T13)
    union { unsigned int u[4]; bf16x8 v; } paA[2][2], paB[2][2];
    SOFTMAX_PACK(saccA, oaccA, mrunA, lrunA, paA);
    SOFTMAX_PACK(saccB, oaccB, mrunB, lrunB, paB);

    // 5. PV both sets; each vf read feeds 2 MFMA
    __builtin_amdgcn_s_setprio(1);
#pragma unroll
    for (int db = 0; db < 4; ++db) {
      int d = db * 32 + l31;
      int dsw = (d >> 3) & 7;
#pragma unroll
      for (int nb = 0; nb < 2; ++nb)
#pragma unroll
        for (int ks = 0; ks < 2; ++ks) {
          int g = nb * 4 + ks * 2 + hi5;
          bf16x8 vf = *(const bf16x8*)(Vtb + d * 36 + 4 * (g ^ dsw));
          oaccA[db] = __builtin_amdgcn_mfma_f32_32x32x16_bf16(vf, paA[nb][ks].v, oaccA[db], 0, 0, 0);
          oaccB[db] = __builtin_amdgcn_mfma_f32_32x32x16_bf16(vf, paB[nb][ks].v, oaccB[db], 0, 0, 0);
        }
    }
    __builtin_amdgcn_s_setprio(0);
    __syncthreads();   // buf bf free for overwrite; buf bf^1 writes visible
  }
#undef LOAD_KV
#undef WRITE_KV
#undef SOFTMAX_PACK

  // ---------- epilogue: O^T -> O via per-wave LDS scratch (reuse VtArr), coalesced ----------
  unsigned short* scr = (unsigned short*)VtArr + wid * 2304;   // 32 rows x 72
#pragma unroll
  for (int set = 0; set < 2; ++set) {
    const f32x16* oacc = set ? oaccB : oaccA;
    float rinv = 1.0f / (set ? lrunB : lrunA);
    long qset = q0 + set * 32;
#pragma unroll
    for (int c = 0; c < 2; ++c) {          // d-chunks [0,64) and [64,128)
      asm volatile("s_waitcnt lgkmcnt(0)" ::: "memory");
      __builtin_amdgcn_sched_barrier(0);
#pragma unroll
      for (int dbh = 0; dbh < 2; ++dbh) {
        int db = 2 * c + dbh;
#pragma unroll
        for (int t = 0; t < 8; ++t) {
          int d_lo = dbh * 32 + ((2 * t) & 3) + 8 * (t >> 1) + 4 * hi5;
          unsigned int pv = cvtpk(oacc[db][2 * t] * rinv, oacc[db][2 * t + 1] * rinv);
          *(unsigned int*)(scr + l31 * 72 + d_lo) = pv;
        }
      }
      asm volatile("s_waitcnt lgkmcnt(0)" ::: "memory");
      __builtin_amdgcn_sched_barrier(0);
#pragma unroll
      for (int j = 0; j < 4; ++j) {
        int row = j * 8 + (lane >> 3);
        bf16x8 ov = *(const bf16x8*)(scr + row * 72 + (lane & 7) * 8);
        *(bf16x8*)(Ob + (rowbase + qset + row) * (long)ND + colbase + c * 64 + (lane & 7) * 8) = ov;
      }
    }
  }
}

// ---------------- launch ----------------
extern "C" void kernel_launch(void* const* d_in, const int* in_sizes, int n_in,
                              void* d_out, int out_size, void* d_ws, size_t ws_size,
                              hipStream_t stream) {
  const float* x = (const float*)d_in[0];
  const float* rope_cos = (const float*)d_in[1];
  const float* rope_sin = (const float*)d_in[2];
  const float* W_q = (const float*)d_in[3];
  const float* W_dkv = (const float*)d_in[4];
  const float* W_uk = (const float*)d_in[5];
  const float* W_uv = (const float*)d_in[6];
  const float* W_o = (const float*)d_in[7];
  float* out = (float*)d_out;

  char* p = (char*)d_ws;
  unsigned short* xb = (unsigned short*)p;    p += (size_t)NROWS * ND * 2;
  unsigned short* Wqb = (unsigned short*)p;   p += (size_t)ND * ND * 2;
  unsigned short* Wdkvb = (unsigned short*)p; p += (size_t)NDC * ND * 2;
  unsigned short* Wukb = (unsigned short*)p;  p += (size_t)ND * NDC * 2;
  unsigned short* Wuvb = (unsigned short*)p;  p += (size_t)ND * NDC * 2;
  unsigned short* Wob = (unsigned short*)p;   p += (size_t)ND * ND * 2;
  unsigned short* Qb = (unsigned short*)p;    p += (size_t)NROWS * ND * 2;
  unsigned short* ckv = (unsigned short*)p;   p += (size_t)NROWS * NDC * 2;
  unsigned short* Kbf = (unsigned short*)p;   p += (size_t)NROWS * ND * 2;
  unsigned short* Vbf = (unsigned short*)p;   p += (size_t)NROWS * ND * 2;
  unsigned short* AO = (unsigned short*)p;    p += (size_t)NROWS * ND * 2;

  // fp32 -> bf16
  {
    struct { const float* s; unsigned short* d; long n; } cv[6] = {
      {x, xb, (long)NROWS * ND},
      {W_q, Wqb, (long)ND * ND},
      {W_dkv, Wdkvb, (long)NDC * ND},
      {W_uk, Wukb, (long)ND * NDC},
      {W_uv, Wuvb, (long)ND * NDC},
      {W_o, Wob, (long)ND * ND},
    };
    for (int i = 0; i < 6; ++i) {
      int n4 = (int)(cv[i].n / 4);
      int blocks = (n4 + 255) / 256;
      if (blocks > 2048) blocks = 2048;
      cvt_kernel<<<blocks, 256, 0, stream>>>((const float4*)cv[i].s, (ushort4*)cv[i].d, n4);
    }
  }

  // projections: 256^2 8-phase for nwg=256 shapes; 128^2 for dkv (N=512)
  gemm_nt256<0><<<dim3(ND / 256, NROWS / 256), 512, 0, stream>>>(xb, Wqb, Qb, NROWS, ND, ND);
  gemm_nt<0><<<dim3(NDC / 128, NROWS / 128), 256, 0, stream>>>(xb, Wdkvb, ckv, NROWS, NDC, ND);
  gemm_nt256<0><<<dim3(ND / 256, NROWS / 256), 512, 0, stream>>>(ckv, Wukb, Kbf, NROWS, ND, NDC);
  gemm_nt256<0><<<dim3(ND / 256, NROWS / 256), 512, 0, stream>>>(ckv, Wuvb, Vbf, NROWS, ND, NDC);

  // RoPE: Q gets 1/sqrt(DH) * log2(e) (softmax uses exp2); K gets 1.0
  const float scale_q = 0.08838834764831845f * 1.4426950408889634f;
  rope_kernel<<<NROWS, 128, 0, stream>>>(Qb, rope_cos, rope_sin, scale_q);
  rope_kernel<<<NROWS, 128, 0, stream>>>(Kbf, rope_cos, rope_sin, 1.0f);

  // attention: 512 blocks of 256 threads (QBLK=256, 64 q/wave)
  flash_attn<<<dim3(8, 64), 256, 0, stream>>>(Qb, Kbf, Vbf, AO);

  // output projection (fp32 out)
  gemm_nt256<1><<<dim3(ND / 256, NROWS / 256), 512, 0, stream>>>(AO, Wob, out, NROWS, ND, ND);
}

// Round 12
// 455.659 us; speedup vs baseline: 1.5413x; 1.0813x over previous
//
#include <hip/hip_runtime.h>
#include <math.h>

typedef __attribute__((ext_vector_type(8))) short bf16x8;
typedef __attribute__((ext_vector_type(4))) float f32x4;
typedef __attribute__((ext_vector_type(16))) float f32x16;

#define NB 4
#define NL 2048
#define ND 2048
#define NH 16
#define NDH 128
#define NDC 512
#define NROWS (NB*NL)

__device__ __forceinline__ unsigned short f2bf(float f) {
  unsigned int u = __float_as_uint(f);
  u += 0x7fffu + ((u >> 16) & 1u);
  return (unsigned short)(u >> 16);
}
__device__ __forceinline__ float bf2f(unsigned short h) {
  return __uint_as_float(((unsigned int)h) << 16);
}
__device__ __forceinline__ unsigned int cvtpk(float lo, float hi) {
  unsigned int r;
  asm("v_cvt_pk_bf16_f32 %0, %1, %2" : "=v"(r) : "v"(lo), "v"(hi));
  return r;
}
// v_permlane32_swap_b32: a.lanes[32:63] <-> b.lanes[0:31]
__device__ __forceinline__ void permswap(unsigned int &a, unsigned int &b) {
  asm("v_permlane32_swap_b32 %0, %1" : "+v"(a), "+v"(b));
}
__device__ __forceinline__ float exp2_fast(float x) {
  float r; asm("v_exp_f32 %0, %1" : "=v"(r) : "v"(x)); return r;
}

__device__ __forceinline__ void gld16(const void* g, void* l) {
  __builtin_amdgcn_global_load_lds((const __attribute__((address_space(1))) void*)g,
                                   (__attribute__((address_space(3))) void*)l, 16, 0, 0);
}

// ---------------- fused fp32 -> bf16 convert (6 segments, one dispatch) ----------------
struct Cvt6 {
  const float4* s[6];
  ushort4* d[6];
  int n4[6];     // float4 counts per segment
};
__global__ void cvt6_kernel(Cvt6 cv, int total4) {
  int stride = gridDim.x * blockDim.x;
  for (int i = blockIdx.x * blockDim.x + threadIdx.x; i < total4; i += stride) {
    int idx = i, seg = 0;
#pragma unroll
    for (int k = 0; k < 5; ++k) {
      if (idx >= cv.n4[seg]) { idx -= cv.n4[seg]; ++seg; }
    }
    float4 v = cv.s[seg][idx];
    ushort4 o;
    o.x = f2bf(v.x); o.y = f2bf(v.y); o.z = f2bf(v.z); o.w = f2bf(v.w);
    cv.d[seg][idx] = o;
  }
}

// ---------------- 128^2 NT GEMM (kept for N=512 shapes) ----------------
template<int OUT_F32>
__global__ __launch_bounds__(256) void gemm_nt(const unsigned short* __restrict__ A,
                                               const unsigned short* __restrict__ Bm,
                                               void* __restrict__ Cv,
                                               int M, int N, int K) {
  __shared__ unsigned short As[128 * 32];
  __shared__ unsigned short Bs[128 * 32];
  const int tid = threadIdx.x;
  const int wid = tid >> 6;
  const int lane = tid & 63;
  const int wr = wid >> 1, wc = wid & 1;
  const long bm = blockIdx.y, bn = blockIdx.x;
  const int r15 = lane & 15;
  const int koff = (lane >> 4) * 8;
  const int srow = lane >> 2;
  const int scol = (lane & 3) * 8;

  f32x4 acc[4][4];
#pragma unroll
  for (int m = 0; m < 4; ++m)
#pragma unroll
    for (int n = 0; n < 4; ++n) acc[m][n] = (f32x4){0.f, 0.f, 0.f, 0.f};

  const unsigned short* Ablk = A + (bm * 128 + wid * 16 + srow) * (long)K + scol;
  const unsigned short* Bblk = Bm + (bn * 128 + wid * 16 + srow) * (long)K + scol;
  unsigned short* AsW = As + wid * 16 * 32;
  unsigned short* BsW = Bs + wid * 16 * 32;

  for (int kk = 0; kk < K; kk += 32) {
    __syncthreads();
#pragma unroll
    for (int j = 0; j < 2; ++j) {
      gld16(Ablk + (long)j * 64 * K + kk, AsW + j * 64 * 32);
      gld16(Bblk + (long)j * 64 * K + kk, BsW + j * 64 * 32);
    }
    __syncthreads();
    bf16x8 af[4], bfr[4];
#pragma unroll
    for (int m = 0; m < 4; ++m)
      af[m] = *(const bf16x8*)(As + (wr * 64 + m * 16 + r15) * 32 + koff);
#pragma unroll
    for (int n = 0; n < 4; ++n)
      bfr[n] = *(const bf16x8*)(Bs + (wc * 64 + n * 16 + r15) * 32 + koff);
#pragma unroll
    for (int m = 0; m < 4; ++m)
#pragma unroll
      for (int n = 0; n < 4; ++n)
        acc[m][n] = __builtin_amdgcn_mfma_f32_16x16x32_bf16(af[m], bfr[n], acc[m][n], 0, 0, 0);
  }

  const int rr = (lane >> 4) * 4;
#pragma unroll
  for (int m = 0; m < 4; ++m) {
#pragma unroll
    for (int n = 0; n < 4; ++n) {
      long row0 = bm * 128 + wr * 64 + m * 16 + rr;
      long col = bn * 128 + wc * 64 + n * 16 + r15;
#pragma unroll
      for (int r = 0; r < 4; ++r) {
        float v = acc[m][n][r];
        if (OUT_F32) ((float*)Cv)[(row0 + r) * (long)N + col] = v;
        else ((unsigned short*)Cv)[(row0 + r) * (long)N + col] = f2bf(v);
      }
    }
  }
}

// ---------------- 256^2 8-phase NT GEMM (T1+T2+T3+T4+T5) ----------------
template<int OUT_F32>
__global__ __launch_bounds__(512) void gemm_nt256(const unsigned short* __restrict__ A,
                                                  const unsigned short* __restrict__ Bm,
                                                  void* __restrict__ Cv,
                                                  int M, int N, int K) {
  __shared__ unsigned short lds[2][2][16384];   // [buf][0=A,1=B][256 rows x 64 cols]
  const int tid = threadIdx.x;
  const int wid = tid >> 6, lane = tid & 63;
  const int wm = wid >> 2, wn = wid & 3;
  const int r15 = lane & 15, khi = lane >> 4;

  const int gx = gridDim.x;
  int bid = blockIdx.y * gx + blockIdx.x;
  int cpx = (gx * gridDim.y) >> 3;
  int swz = (bid & 7) * cpx + (bid >> 3);
  const long bm = swz / gx, bn = swz % gx;

  const int c0 = tid, c1 = 512 + tid;
  const int r0 = c0 >> 3, r1 = c1 >> 3;
  const int cs0 = ((c0 & 7) ^ (r0 & 7)) * 8;
  const int cs1 = ((c1 & 7) ^ (r1 & 7)) * 8;
  const unsigned short* srcA = A + (bm * 256) * (long)K;
  const unsigned short* srcB = Bm + (bn * 256) * (long)K;

#define STAGE256(mat, h, kb, bufi) do {                                              \
    const unsigned short* s_ = (mat) ? srcB : srcA;                                  \
    gld16(s_ + ((h) * 128 + r0) * (long)K + (kb) + cs0,                              \
          &lds[bufi][mat][(h) * 8192 + wid * 512]);                                  \
    gld16(s_ + ((h) * 128 + r1) * (long)K + (kb) + cs1,                              \
          &lds[bufi][mat][(h) * 8192 + 4096 + wid * 512]);                           \
  } while (0)

  f32x4 acc[8][4];
#pragma unroll
  for (int m = 0; m < 8; ++m)
#pragma unroll
    for (int n = 0; n < 4; ++n) acc[m][n] = (f32x4){0.f, 0.f, 0.f, 0.f};

  const int NT = K >> 6;
  STAGE256(0, 0, 0, 0); STAGE256(0, 1, 0, 0);
  STAGE256(1, 0, 0, 0); STAGE256(1, 1, 0, 0);

  for (int t = 0; t < NT; ++t) {
    const int buf = t & 1, nbuf = buf ^ 1;
    const int kb1 = (t + 1) << 6;
    const bool pf = (t + 1 < NT);
    __builtin_amdgcn_s_barrier();
    if (pf) {
      STAGE256(0, 0, kb1, nbuf);
      asm volatile("s_waitcnt vmcnt(2)" ::: "memory");
    } else {
      asm volatile("s_waitcnt vmcnt(0)" ::: "memory");
    }
    __builtin_amdgcn_s_barrier();

    bf16x8 bfr[4][2];
#pragma unroll
    for (int n = 0; n < 4; ++n)
#pragma unroll
      for (int kk = 0; kk < 2; ++kk) {
        int rb = wn * 64 + n * 16 + r15;
        bfr[n][kk] = *(const bf16x8*)&lds[buf][1][rb * 64 + (((kk * 4 + khi) ^ (rb & 7)) * 8)];
      }
#pragma unroll
    for (int mb = 0; mb < 4; ++mb) {
      if (mb != 0) {
        __builtin_amdgcn_s_barrier();
        if (pf) {
          if (mb == 1) STAGE256(0, 1, kb1, nbuf);
          else if (mb == 2) STAGE256(1, 0, kb1, nbuf);
          else STAGE256(1, 1, kb1, nbuf);
        }
      }
      bf16x8 af[2][2];
#pragma unroll
      for (int m2 = 0; m2 < 2; ++m2)
#pragma unroll
        for (int kk = 0; kk < 2; ++kk) {
          int ra = wm * 128 + mb * 32 + m2 * 16 + r15;
          af[m2][kk] = *(const bf16x8*)&lds[buf][0][ra * 64 + (((kk * 4 + khi) ^ (ra & 7)) * 8)];
        }
      asm volatile("s_waitcnt lgkmcnt(0)" ::: "memory");
      __builtin_amdgcn_sched_barrier(0);
      __builtin_amdgcn_s_setprio(1);
#pragma unroll
      for (int m2 = 0; m2 < 2; ++m2)
#pragma unroll
        for (int n = 0; n < 4; ++n)
#pragma unroll
          for (int kk = 0; kk < 2; ++kk)
            acc[mb * 2 + m2][n] = __builtin_amdgcn_mfma_f32_16x16x32_bf16(
                af[m2][kk], bfr[n][kk], acc[mb * 2 + m2][n], 0, 0, 0);
      __builtin_amdgcn_s_setprio(0);
    }
  }
#undef STAGE256

#pragma unroll
  for (int mi = 0; mi < 8; ++mi) {
#pragma unroll
    for (int n = 0; n < 4; ++n) {
      long row0 = bm * 256 + wm * 128 + mi * 16 + khi * 4;
      long col = bn * 256 + wn * 64 + n * 16 + r15;
#pragma unroll
      for (int r = 0; r < 4; ++r) {
        float v = acc[mi][n][r];
        if (OUT_F32) ((float*)Cv)[(row0 + r) * (long)N + col] = v;
        else ((unsigned short*)Cv)[(row0 + r) * (long)N + col] = f2bf(v);
      }
    }
  }
}

// ---------------- RoPE in-place (vectorized: 8 pairs/thread, bf16x8 loads) ----------------
__global__ void rope_kernel(unsigned short* __restrict__ Qb, const float* __restrict__ cosb,
                            const float* __restrict__ sinb, float scale) {
  const long row = blockIdx.x;
  const int p = threadIdx.x;            // 0..127
  const int h = p >> 3, d8 = (p & 7) * 8;
  const float* cr = cosb + row * NDH;
  const float* sr = sinb + row * NDH;
  unsigned short* q = Qb + row * (long)ND + h * 128 + d8;

  bf16x8 qlo = *(const bf16x8*)(q);
  bf16x8 qhi = *(const bf16x8*)(q + 64);
  float4 c0 = *(const float4*)(cr + d8), c1 = *(const float4*)(cr + d8 + 4);
  float4 c2 = *(const float4*)(cr + d8 + 64), c3 = *(const float4*)(cr + d8 + 68);
  float4 s0 = *(const float4*)(sr + d8), s1 = *(const float4*)(sr + d8 + 4);
  float4 s2 = *(const float4*)(sr + d8 + 64), s3 = *(const float4*)(sr + d8 + 68);
  float cl[8] = {c0.x, c0.y, c0.z, c0.w, c1.x, c1.y, c1.z, c1.w};
  float ch[8] = {c2.x, c2.y, c2.z, c2.w, c3.x, c3.y, c3.z, c3.w};
  float sl[8] = {s0.x, s0.y, s0.z, s0.w, s1.x, s1.y, s1.z, s1.w};
  float sh[8] = {s2.x, s2.y, s2.z, s2.w, s3.x, s3.y, s3.z, s3.w};
  bf16x8 olo, ohi;
#pragma unroll
  for (int i = 0; i < 8; ++i) {
    float q1 = bf2f((unsigned short)qlo[i]);
    float q2 = bf2f((unsigned short)qhi[i]);
    olo[i] = (short)f2bf((q1 * cl[i] - q2 * sl[i]) * scale);
    ohi[i] = (short)f2bf((q2 * ch[i] + q1 * sh[i]) * scale);
  }
  *(bf16x8*)(q) = olo;
  *(bf16x8*)(q + 64) = ohi;
}

// ---------------- Flash attention v8 (proven 170us config, reverted) ----------------
// 512 thr = 8 waves, 32 q/wave, QBLK=256, grid (8,64) XCD bh-grouping.
// Dbuf K/V LDS one-barrier/tile; Ks XOR (row&15)<<3; Vt packed-u32; T12 cvt_pk+permlane;
// T13 defer-max; exp2 softmax; T5 setprio.
__global__ __launch_bounds__(512) void flash_attn(const unsigned short* __restrict__ Qb,
                                                  const unsigned short* __restrict__ Kb,
                                                  const unsigned short* __restrict__ Vb,
                                                  unsigned short* __restrict__ Ob) {
  __shared__ unsigned short KsArr[2 * 8192];   // [buf][key*128 + (c ^ ((key&15)<<3))]
  __shared__ unsigned int VtArr[2 * 4608];     // [buf][d*36 + 4*((kp>>2)^((d>>3)&7)) + (kp&3)]

  const int tid = threadIdx.x, wid = tid >> 6, lane = tid & 63;
  const int l31 = lane & 31, hi5 = lane >> 5;

  // XCD bh-grouping: linear L -> bh = (L>>6)*8 + (L&7), qt = (L>>3)&7
  const int L = blockIdx.y * 8 + blockIdx.x;
  const int bh = ((L >> 6) << 3) | (L & 7);
  const int qt = (L >> 3) & 7;
  const int b = bh >> 4, h = bh & 15;
  const long rowbase = (long)b * NL;
  const int colbase = h * NDH;
  const long q0 = (long)qt * 256 + wid * 32;

  // Q fragments: B-operand, col = q = l31, k = kc*16 + hi5*8 + j
  bf16x8 qf[8];
  {
    const unsigned short* qp = Qb + (rowbase + q0 + l31) * (long)ND + colbase + hi5 * 8;
#pragma unroll
    for (int kc = 0; kc < 8; ++kc) qf[kc] = *(const bf16x8*)(qp + kc * 16);
  }

  f32x16 oacc[4];
#pragma unroll
  for (int db = 0; db < 4; ++db)
#pragma unroll
    for (int i = 0; i < 16; ++i) oacc[db][i] = 0.f;
  float mrun = -1e30f, lrun = 0.f;

  // staging: thread covers keys (2kp, 2kp+1) at d-cols c8..c8+7
  const int kp = tid >> 4;                 // 0..31
  const int c8 = (tid & 15) * 8;
  bf16x8 kreg[2], vreg[2];

#define LOAD_KV(kt_) do {                                                          \
    _Pragma("unroll") for (int j = 0; j < 2; ++j) {                                \
      const long grow = (rowbase + (kt_) * 64 + 2 * kp + j) * (long)ND + colbase + c8; \
      kreg[j] = *(const bf16x8*)(Kb + grow);                                       \
      vreg[j] = *(const bf16x8*)(Vb + grow);                                       \
    } } while (0)

#define WRITE_KV(bi) do {                                                          \
    _Pragma("unroll") for (int j = 0; j < 2; ++j) {                                \
      int row_ = 2 * kp + j;                                                       \
      *(bf16x8*)(KsArr + (bi) * 8192 + row_ * 128 + (c8 ^ ((row_ & 15) << 3))) = kreg[j]; \
    }                                                                              \
    _Pragma("unroll") for (int i = 0; i < 8; ++i) {                                \
      int d_ = c8 + i;                                                             \
      VtArr[(bi) * 4608 + d_ * 36 + 4 * ((kp >> 2) ^ ((d_ >> 3) & 7)) + (kp & 3)] = \
          (unsigned int)(unsigned short)vreg[0][i] |                               \
          ((unsigned int)(unsigned short)vreg[1][i] << 16);                        \
    } } while (0)

  // prologue: tile 0 -> buf 0; then prefetch tile 1
  LOAD_KV(0);
  WRITE_KV(0);
  __syncthreads();
  LOAD_KV(1);

  const int NT = NL / 64;
  for (int kt = 0; kt < NT; ++kt) {
    const int bf = kt & 1;
    const unsigned short* Ksb = KsArr + bf * 8192;
    const unsigned int* Vtb = VtArr + bf * 4608;

    // 1. S^T = mfma32(K, Q) from buf bf
    f32x16 sacc[2];
    __builtin_amdgcn_s_setprio(1);
#pragma unroll
    for (int nb = 0; nb < 2; ++nb) {
#pragma unroll
      for (int i = 0; i < 16; ++i) sacc[nb][i] = 0.f;
#pragma unroll
      for (int kc = 0; kc < 8; ++kc) {
        int row = nb * 32 + l31;
        bf16x8 kf = *(const bf16x8*)(Ksb + row * 128 + ((kc * 16 + hi5 * 8) ^ ((row & 15) << 3)));
        sacc[nb] = __builtin_amdgcn_mfma_f32_32x32x16_bf16(kf, qf[kc], sacc[nb], 0, 0, 0);
      }
    }
    __builtin_amdgcn_s_setprio(0);

    // 2. stage tile kt+1 regs -> other buffer (overlaps softmax below)
    if (kt + 1 < NT) WRITE_KV(bf ^ 1);
    // 3. prefetch tile kt+2 -> regs
    if (kt + 2 < NT) LOAD_KV(kt + 2);

    // 4. lane-local online softmax (base-2; log2e pre-folded into Q scale), tree reduce
    float mxa[8];
#pragma unroll
    for (int i = 0; i < 8; ++i)
      mxa[i] = fmaxf(fmaxf(sacc[0][i], sacc[0][i + 8]), fmaxf(sacc[1][i], sacc[1][i + 8]));
    float mx = fmaxf(fmaxf(fmaxf(mxa[0], mxa[1]), fmaxf(mxa[2], mxa[3])),
                     fmaxf(fmaxf(mxa[4], mxa[5]), fmaxf(mxa[6], mxa[7])));
    mx = fmaxf(mx, __shfl_xor(mx, 32));
    if (!__all(mx - mrun <= 8.f)) {            // defer-max (T13)
      float mnew = fmaxf(mrun, mx);
      float corr = exp2_fast(mrun - mnew);
      mrun = mnew;
      lrun *= corr;
#pragma unroll
      for (int db = 0; db < 4; ++db)
#pragma unroll
        for (int i = 0; i < 16; ++i) oacc[db][i] *= corr;
    }
    float s4[4] = {0.f, 0.f, 0.f, 0.f};
#pragma unroll
    for (int nb = 0; nb < 2; ++nb)
#pragma unroll
      for (int r = 0; r < 16; ++r) {
        float e = exp2_fast(sacc[nb][r] - mrun);
        sacc[nb][r] = e;
        s4[r & 3] += e;
      }
    float s = (s4[0] + s4[1]) + (s4[2] + s4[3]);
    s += __shfl_xor(s, 32);
    lrun += s;

    // P -> B-operand frags: cvt_pk + permlane32_swap (T12), no LDS-pipe traffic
    union { unsigned int u[4]; bf16x8 v; } pa[2][2];
#pragma unroll
    for (int nb = 0; nb < 2; ++nb) {
      unsigned int x1 = cvtpk(sacc[nb][0], sacc[nb][1]);
      unsigned int x2 = cvtpk(sacc[nb][2], sacc[nb][3]);
      unsigned int y1 = cvtpk(sacc[nb][4], sacc[nb][5]);
      unsigned int y2 = cvtpk(sacc[nb][6], sacc[nb][7]);
      unsigned int z1 = cvtpk(sacc[nb][8], sacc[nb][9]);
      unsigned int z2 = cvtpk(sacc[nb][10], sacc[nb][11]);
      unsigned int w1 = cvtpk(sacc[nb][12], sacc[nb][13]);
      unsigned int w2 = cvtpk(sacc[nb][14], sacc[nb][15]);
      permswap(x1, y1);   // x1: u[0]; y1: u[2]
      permswap(x2, y2);
      permswap(z1, w1);
      permswap(z2, w2);
      pa[nb][0].u[0] = x1; pa[nb][0].u[1] = x2; pa[nb][0].u[2] = y1; pa[nb][0].u[3] = y2;
      pa[nb][1].u[0] = z1; pa[nb][1].u[1] = z2; pa[nb][1].u[2] = w1; pa[nb][1].u[3] = w2;
    }

    // 5. PV: O^T[d][q] += V^T-frag x P-frag from buf bf
    __builtin_amdgcn_s_setprio(1);
#pragma unroll
    for (int db = 0; db < 4; ++db) {
      int d = db * 32 + l31;
      int dsw = (d >> 3) & 7;
#pragma unroll
      for (int nb = 0; nb < 2; ++nb)
#pragma unroll
        for (int ks = 0; ks < 2; ++ks) {
          int g = nb * 4 + ks * 2 + hi5;
          bf16x8 vf = *(const bf16x8*)(Vtb + d * 36 + 4 * (g ^ dsw));
          oacc[db] = __builtin_amdgcn_mfma_f32_32x32x16_bf16(vf, pa[nb][ks].v, oacc[db], 0, 0, 0);
        }
    }
    __builtin_amdgcn_s_setprio(0);
    __syncthreads();   // buf bf free for overwrite; buf bf^1 writes visible
  }
#undef LOAD_KV
#undef WRITE_KV

  // ---------- epilogue: O^T -> O via per-wave LDS scratch (reuse VtArr), coalesced ----------
  float rinv = 1.0f / lrun;
  unsigned short* scr = (unsigned short*)VtArr + wid * 2304;   // 32 rows x 72
#pragma unroll
  for (int c = 0; c < 2; ++c) {          // d-chunks [0,64) and [64,128)
    asm volatile("s_waitcnt lgkmcnt(0)" ::: "memory");
    __builtin_amdgcn_sched_barrier(0);
#pragma unroll
    for (int dbh = 0; dbh < 2; ++dbh) {
      int db = 2 * c + dbh;
#pragma unroll
      for (int t = 0; t < 8; ++t) {
        int d_lo = dbh * 32 + ((2 * t) & 3) + 8 * (t >> 1) + 4 * hi5;
        unsigned int pv = cvtpk(oacc[db][2 * t] * rinv, oacc[db][2 * t + 1] * rinv);
        *(unsigned int*)(scr + l31 * 72 + d_lo) = pv;
      }
    }
    asm volatile("s_waitcnt lgkmcnt(0)" ::: "memory");
    __builtin_amdgcn_sched_barrier(0);
#pragma unroll
    for (int j = 0; j < 4; ++j) {
      int row = j * 8 + (lane >> 3);
      bf16x8 ov = *(const bf16x8*)(scr + row * 72 + (lane & 7) * 8);
      *(bf16x8*)(Ob + (rowbase + q0 + row) * (long)ND + colbase + c * 64 + (lane & 7) * 8) = ov;
    }
  }
}

// ---------------- launch ----------------
extern "C" void kernel_launch(void* const* d_in, const int* in_sizes, int n_in,
                              void* d_out, int out_size, void* d_ws, size_t ws_size,
                              hipStream_t stream) {
  const float* x = (const float*)d_in[0];
  const float* rope_cos = (const float*)d_in[1];
  const float* rope_sin = (const float*)d_in[2];
  const float* W_q = (const float*)d_in[3];
  const float* W_dkv = (const float*)d_in[4];
  const float* W_uk = (const float*)d_in[5];
  const float* W_uv = (const float*)d_in[6];
  const float* W_o = (const float*)d_in[7];
  float* out = (float*)d_out;

  char* p = (char*)d_ws;
  unsigned short* xb = (unsigned short*)p;    p += (size_t)NROWS * ND * 2;
  unsigned short* Wqb = (unsigned short*)p;   p += (size_t)ND * ND * 2;
  unsigned short* Wdkvb = (unsigned short*)p; p += (size_t)NDC * ND * 2;
  unsigned short* Wukb = (unsigned short*)p;  p += (size_t)ND * NDC * 2;
  unsigned short* Wuvb = (unsigned short*)p;  p += (size_t)ND * NDC * 2;
  unsigned short* Wob = (unsigned short*)p;   p += (size_t)ND * ND * 2;
  unsigned short* Qb = (unsigned short*)p;    p += (size_t)NROWS * ND * 2;
  unsigned short* ckv = (unsigned short*)p;   p += (size_t)NROWS * NDC * 2;
  unsigned short* Kbf = (unsigned short*)p;   p += (size_t)NROWS * ND * 2;
  unsigned short* Vbf = (unsigned short*)p;   p += (size_t)NROWS * ND * 2;
  unsigned short* AO = (unsigned short*)p;    p += (size_t)NROWS * ND * 2;

  // fused fp32 -> bf16 (one dispatch, 6 segments)
  {
    Cvt6 cv;
    const float* ss[6] = {x, W_q, W_dkv, W_uk, W_uv, W_o};
    unsigned short* dd[6] = {xb, Wqb, Wdkvb, Wukb, Wuvb, Wob};
    long nn[6] = {(long)NROWS * ND, (long)ND * ND, (long)NDC * ND,
                  (long)ND * NDC, (long)ND * NDC, (long)ND * ND};
    int total4 = 0;
    for (int i = 0; i < 6; ++i) {
      cv.s[i] = (const float4*)ss[i];
      cv.d[i] = (ushort4*)dd[i];
      cv.n4[i] = (int)(nn[i] / 4);
      total4 += cv.n4[i];
    }
    cvt6_kernel<<<2048, 256, 0, stream>>>(cv, total4);
  }

  // projections: 256^2 8-phase for nwg=256 shapes; 128^2 for dkv (N=512)
  gemm_nt256<0><<<dim3(ND / 256, NROWS / 256), 512, 0, stream>>>(xb, Wqb, Qb, NROWS, ND, ND);
  gemm_nt<0><<<dim3(NDC / 128, NROWS / 128), 256, 0, stream>>>(xb, Wdkvb, ckv, NROWS, NDC, ND);
  gemm_nt256<0><<<dim3(ND / 256, NROWS / 256), 512, 0, stream>>>(ckv, Wukb, Kbf, NROWS, ND, NDC);
  gemm_nt256<0><<<dim3(ND / 256, NROWS / 256), 512, 0, stream>>>(ckv, Wuvb, Vbf, NROWS, ND, NDC);

  // RoPE: Q gets 1/sqrt(DH) * log2(e) (softmax uses exp2); K gets 1.0
  const float scale_q = 0.08838834764831845f * 1.4426950408889634f;
  rope_kernel<<<NROWS, 128, 0, stream>>>(Qb, rope_cos, rope_sin, scale_q);
  rope_kernel<<<NROWS, 128, 0, stream>>>(Kbf, rope_cos, rope_sin, 1.0f);

  // attention: 512 blocks of 512 threads (QBLK=256, 32 q/wave) — proven v8 config
  flash_attn<<<dim3(8, 64), 512, 0, stream>>>(Qb, Kbf, Vbf, AO);

  // output projection (fp32 out)
  gemm_nt256<1><<<dim3(ND / 256, NROWS / 256), 512, 0, stream>>>(AO, Wob, out, NROWS, ND, ND);
}

// Round 13
// 423.910 us; speedup vs baseline: 1.6567x; 1.0749x over previous
//
#include <hip/hip_runtime.h>
#include <math.h>

typedef __attribute__((ext_vector_type(8))) short bf16x8;
typedef __attribute__((ext_vector_type(4))) float f32x4;
typedef __attribute__((ext_vector_type(16))) float f32x16;

#define NB 4
#define NL 2048
#define ND 2048
#define NH 16
#define NDH 128
#define NDC 512
#define NROWS (NB*NL)

__device__ __forceinline__ unsigned short f2bf(float f) {
  unsigned int u = __float_as_uint(f);
  u += 0x7fffu + ((u >> 16) & 1u);
  return (unsigned short)(u >> 16);
}
__device__ __forceinline__ float bf2f(unsigned short h) {
  return __uint_as_float(((unsigned int)h) << 16);
}
__device__ __forceinline__ unsigned int cvtpk(float lo, float hi) {
  unsigned int r;
  asm("v_cvt_pk_bf16_f32 %0, %1, %2" : "=v"(r) : "v"(lo), "v"(hi));
  return r;
}
// v_permlane32_swap_b32: a.lanes[32:63] <-> b.lanes[0:31]
__device__ __forceinline__ void permswap(unsigned int &a, unsigned int &b) {
  asm("v_permlane32_swap_b32 %0, %1" : "+v"(a), "+v"(b));
}
__device__ __forceinline__ float exp2_fast(float x) {
  float r; asm("v_exp_f32 %0, %1" : "=v"(r) : "v"(x)); return r;
}

__device__ __forceinline__ void gld16(const void* g, void* l) {
  __builtin_amdgcn_global_load_lds((const __attribute__((address_space(1))) void*)g,
                                   (__attribute__((address_space(3))) void*)l, 16, 0, 0);
}

// ---------------- fp32 -> bf16 convert ----------------
__global__ void cvt_kernel(const float4* __restrict__ in, ushort4* __restrict__ out, int n4) {
  int stride = gridDim.x * blockDim.x;
  for (int i = blockIdx.x * blockDim.x + threadIdx.x; i < n4; i += stride) {
    float4 v = in[i];
    ushort4 o;
    o.x = f2bf(v.x); o.y = f2bf(v.y); o.z = f2bf(v.z); o.w = f2bf(v.w);
    out[i] = o;
  }
}

// ---------------- 128^2 NT GEMM (kept for N=512 shapes) ----------------
template<int OUT_F32>
__global__ __launch_bounds__(256) void gemm_nt(const unsigned short* __restrict__ A,
                                               const unsigned short* __restrict__ Bm,
                                               void* __restrict__ Cv,
                                               int M, int N, int K) {
  __shared__ unsigned short As[128 * 32];
  __shared__ unsigned short Bs[128 * 32];
  const int tid = threadIdx.x;
  const int wid = tid >> 6;
  const int lane = tid & 63;
  const int wr = wid >> 1, wc = wid & 1;
  const long bm = blockIdx.y, bn = blockIdx.x;
  const int r15 = lane & 15;
  const int koff = (lane >> 4) * 8;
  const int srow = lane >> 2;
  const int scol = (lane & 3) * 8;

  f32x4 acc[4][4];
#pragma unroll
  for (int m = 0; m < 4; ++m)
#pragma unroll
    for (int n = 0; n < 4; ++n) acc[m][n] = (f32x4){0.f, 0.f, 0.f, 0.f};

  const unsigned short* Ablk = A + (bm * 128 + wid * 16 + srow) * (long)K + scol;
  const unsigned short* Bblk = Bm + (bn * 128 + wid * 16 + srow) * (long)K + scol;
  unsigned short* AsW = As + wid * 16 * 32;
  unsigned short* BsW = Bs + wid * 16 * 32;

  for (int kk = 0; kk < K; kk += 32) {
    __syncthreads();
#pragma unroll
    for (int j = 0; j < 2; ++j) {
      gld16(Ablk + (long)j * 64 * K + kk, AsW + j * 64 * 32);
      gld16(Bblk + (long)j * 64 * K + kk, BsW + j * 64 * 32);
    }
    __syncthreads();
    bf16x8 af[4], bfr[4];
#pragma unroll
    for (int m = 0; m < 4; ++m)
      af[m] = *(const bf16x8*)(As + (wr * 64 + m * 16 + r15) * 32 + koff);
#pragma unroll
    for (int n = 0; n < 4; ++n)
      bfr[n] = *(const bf16x8*)(Bs + (wc * 64 + n * 16 + r15) * 32 + koff);
#pragma unroll
    for (int m = 0; m < 4; ++m)
#pragma unroll
      for (int n = 0; n < 4; ++n)
        acc[m][n] = __builtin_amdgcn_mfma_f32_16x16x32_bf16(af[m], bfr[n], acc[m][n], 0, 0, 0);
  }

  const int rr = (lane >> 4) * 4;
#pragma unroll
  for (int m = 0; m < 4; ++m) {
#pragma unroll
    for (int n = 0; n < 4; ++n) {
      long row0 = bm * 128 + wr * 64 + m * 16 + rr;
      long col = bn * 128 + wc * 64 + n * 16 + r15;
#pragma unroll
      for (int r = 0; r < 4; ++r) {
        float v = acc[m][n][r];
        if (OUT_F32) ((float*)Cv)[(row0 + r) * (long)N + col] = v;
        else ((unsigned short*)Cv)[(row0 + r) * (long)N + col] = f2bf(v);
      }
    }
  }
}

// ---------------- 256^2 8-phase NT GEMM (T1+T2+T3+T4+T5), optional fused RoPE ----------------
// ROPE=1: output cols are heads of 128; epilogue stages the 256x256 bf16 tile in the
// (now dead) 128KB LDS, applies rotary (pairs d, d+64 within a head) with rscale,
// stores coalesced bf16x8. cosb/sinb are [row][128] fp32.
template<int OUT_F32, int ROPE>
__global__ __launch_bounds__(512) void gemm_nt256(const unsigned short* __restrict__ A,
                                                  const unsigned short* __restrict__ Bm,
                                                  void* __restrict__ Cv,
                                                  int M, int N, int K,
                                                  const float* __restrict__ cosb,
                                                  const float* __restrict__ sinb,
                                                  float rscale) {
  __shared__ unsigned short lds[2][2][16384];   // [buf][0=A,1=B][256 rows x 64 cols]
  const int tid = threadIdx.x;
  const int wid = tid >> 6, lane = tid & 63;
  const int wm = wid >> 2, wn = wid & 3;
  const int r15 = lane & 15, khi = lane >> 4;

  const int gx = gridDim.x;
  int bid = blockIdx.y * gx + blockIdx.x;
  int cpx = (gx * gridDim.y) >> 3;
  int swz = (bid & 7) * cpx + (bid >> 3);
  const long bm = swz / gx, bn = swz % gx;

  const int c0 = tid, c1 = 512 + tid;
  const int r0 = c0 >> 3, r1 = c1 >> 3;
  const int cs0 = ((c0 & 7) ^ (r0 & 7)) * 8;
  const int cs1 = ((c1 & 7) ^ (r1 & 7)) * 8;
  const unsigned short* srcA = A + (bm * 256) * (long)K;
  const unsigned short* srcB = Bm + (bn * 256) * (long)K;

#define STAGE256(mat, h, kb, bufi) do {                                              \
    const unsigned short* s_ = (mat) ? srcB : srcA;                                  \
    gld16(s_ + ((h) * 128 + r0) * (long)K + (kb) + cs0,                              \
          &lds[bufi][mat][(h) * 8192 + wid * 512]);                                  \
    gld16(s_ + ((h) * 128 + r1) * (long)K + (kb) + cs1,                              \
          &lds[bufi][mat][(h) * 8192 + 4096 + wid * 512]);                           \
  } while (0)

  f32x4 acc[8][4];
#pragma unroll
  for (int m = 0; m < 8; ++m)
#pragma unroll
    for (int n = 0; n < 4; ++n) acc[m][n] = (f32x4){0.f, 0.f, 0.f, 0.f};

  const int NT = K >> 6;
  STAGE256(0, 0, 0, 0); STAGE256(0, 1, 0, 0);
  STAGE256(1, 0, 0, 0); STAGE256(1, 1, 0, 0);

  for (int t = 0; t < NT; ++t) {
    const int buf = t & 1, nbuf = buf ^ 1;
    const int kb1 = (t + 1) << 6;
    const bool pf = (t + 1 < NT);
    __builtin_amdgcn_s_barrier();
    if (pf) {
      STAGE256(0, 0, kb1, nbuf);
      asm volatile("s_waitcnt vmcnt(2)" ::: "memory");
    } else {
      asm volatile("s_waitcnt vmcnt(0)" ::: "memory");
    }
    __builtin_amdgcn_s_barrier();

    bf16x8 bfr[4][2];
#pragma unroll
    for (int n = 0; n < 4; ++n)
#pragma unroll
      for (int kk = 0; kk < 2; ++kk) {
        int rb = wn * 64 + n * 16 + r15;
        bfr[n][kk] = *(const bf16x8*)&lds[buf][1][rb * 64 + (((kk * 4 + khi) ^ (rb & 7)) * 8)];
      }
#pragma unroll
    for (int mb = 0; mb < 4; ++mb) {
      if (mb != 0) {
        __builtin_amdgcn_s_barrier();
        if (pf) {
          if (mb == 1) STAGE256(0, 1, kb1, nbuf);
          else if (mb == 2) STAGE256(1, 0, kb1, nbuf);
          else STAGE256(1, 1, kb1, nbuf);
        }
      }
      bf16x8 af[2][2];
#pragma unroll
      for (int m2 = 0; m2 < 2; ++m2)
#pragma unroll
        for (int kk = 0; kk < 2; ++kk) {
          int ra = wm * 128 + mb * 32 + m2 * 16 + r15;
          af[m2][kk] = *(const bf16x8*)&lds[buf][0][ra * 64 + (((kk * 4 + khi) ^ (ra & 7)) * 8)];
        }
      asm volatile("s_waitcnt lgkmcnt(0)" ::: "memory");
      __builtin_amdgcn_sched_barrier(0);
      __builtin_amdgcn_s_setprio(1);
#pragma unroll
      for (int m2 = 0; m2 < 2; ++m2)
#pragma unroll
        for (int n = 0; n < 4; ++n)
#pragma unroll
          for (int kk = 0; kk < 2; ++kk)
            acc[mb * 2 + m2][n] = __builtin_amdgcn_mfma_f32_16x16x32_bf16(
                af[m2][kk], bfr[n][kk], acc[mb * 2 + m2][n], 0, 0, 0);
      __builtin_amdgcn_s_setprio(0);
    }
  }
#undef STAGE256

  if (ROPE) {
    // ---- fused rotary epilogue via LDS tile (256x256 bf16 = exactly 128KB) ----
    __syncthreads();
    unsigned short* scr = (unsigned short*)lds;   // col ^ ((row>>2)&3)<<4 swizzle
#pragma unroll
    for (int mi = 0; mi < 8; ++mi)
#pragma unroll
      for (int n = 0; n < 4; ++n) {
        int coll = wn * 64 + n * 16 + r15;
#pragma unroll
        for (int r = 0; r < 4; ++r) {
          int rowl = wm * 128 + mi * 16 + khi * 4 + r;
          scr[rowl * 256 + (coll ^ (((rowl >> 2) & 3) << 4))] = f2bf(acc[mi][n][r]);
        }
      }
    __syncthreads();
    const int d8 = (tid & 7) * 8;
#pragma unroll
    for (int j = 0; j < 8; ++j) {
      int rh = j * 64 + (tid >> 3);
      int rowl = rh >> 1, head = rh & 1;
      long grow = bm * 256 + rowl;
      const float* cr = cosb + grow * NDH;
      const float* sr = sinb + grow * NDH;
      int sw = ((rowl >> 2) & 3) << 4;
      int cl_ = head * 128 + d8;
      bf16x8 qlo = *(const bf16x8*)(scr + rowl * 256 + (cl_ ^ sw));
      bf16x8 qhi = *(const bf16x8*)(scr + rowl * 256 + ((cl_ + 64) ^ sw));
      float4 cA = *(const float4*)(cr + d8), cB = *(const float4*)(cr + d8 + 4);
      float4 cC = *(const float4*)(cr + d8 + 64), cD = *(const float4*)(cr + d8 + 68);
      float4 sA = *(const float4*)(sr + d8), sB = *(const float4*)(sr + d8 + 4);
      float4 sC = *(const float4*)(sr + d8 + 64), sD = *(const float4*)(sr + d8 + 68);
      float clo[8] = {cA.x, cA.y, cA.z, cA.w, cB.x, cB.y, cB.z, cB.w};
      float chi[8] = {cC.x, cC.y, cC.z, cC.w, cD.x, cD.y, cD.z, cD.w};
      float slo[8] = {sA.x, sA.y, sA.z, sA.w, sB.x, sB.y, sB.z, sB.w};
      float shi[8] = {sC.x, sC.y, sC.z, sC.w, sD.x, sD.y, sD.z, sD.w};
      bf16x8 olo, ohi;
#pragma unroll
      for (int i = 0; i < 8; ++i) {
        float q1 = bf2f((unsigned short)qlo[i]);
        float q2 = bf2f((unsigned short)qhi[i]);
        olo[i] = (short)f2bf((q1 * clo[i] - q2 * slo[i]) * rscale);
        ohi[i] = (short)f2bf((q2 * chi[i] + q1 * shi[i]) * rscale);
      }
      unsigned short* op = (unsigned short*)Cv + grow * (long)N + bn * 256 + cl_;
      *(bf16x8*)op = olo;
      *(bf16x8*)(op + 64) = ohi;
    }
  } else {
#pragma unroll
    for (int mi = 0; mi < 8; ++mi) {
#pragma unroll
      for (int n = 0; n < 4; ++n) {
        long row0 = bm * 256 + wm * 128 + mi * 16 + khi * 4;
        long col = bn * 256 + wn * 64 + n * 16 + r15;
#pragma unroll
        for (int r = 0; r < 4; ++r) {
          float v = acc[mi][n][r];
          if (OUT_F32) ((float*)Cv)[(row0 + r) * (long)N + col] = v;
          else ((unsigned short*)Cv)[(row0 + r) * (long)N + col] = f2bf(v);
        }
      }
    }
  }
}

// ---------------- Flash attention v8 (proven config) ----------------
// 512 thr = 8 waves, 32 q/wave, QBLK=256, grid (8,64) XCD bh-grouping.
// Dbuf K/V LDS one-barrier/tile; Ks XOR (row&15)<<3; Vt packed-u32; T12 cvt_pk+permlane;
// T13 defer-max; exp2 softmax; T5 setprio.
__global__ __launch_bounds__(512) void flash_attn(const unsigned short* __restrict__ Qb,
                                                  const unsigned short* __restrict__ Kb,
                                                  const unsigned short* __restrict__ Vb,
                                                  unsigned short* __restrict__ Ob) {
  __shared__ unsigned short KsArr[2 * 8192];   // [buf][key*128 + (c ^ ((key&15)<<3))]
  __shared__ unsigned int VtArr[2 * 4608];     // [buf][d*36 + 4*((kp>>2)^((d>>3)&7)) + (kp&3)]

  const int tid = threadIdx.x, wid = tid >> 6, lane = tid & 63;
  const int l31 = lane & 31, hi5 = lane >> 5;

  // XCD bh-grouping: linear L -> bh = (L>>6)*8 + (L&7), qt = (L>>3)&7
  const int L = blockIdx.y * 8 + blockIdx.x;
  const int bh = ((L >> 6) << 3) | (L & 7);
  const int qt = (L >> 3) & 7;
  const int b = bh >> 4, h = bh & 15;
  const long rowbase = (long)b * NL;
  const int colbase = h * NDH;
  const long q0 = (long)qt * 256 + wid * 32;

  // Q fragments: B-operand, col = q = l31, k = kc*16 + hi5*8 + j
  bf16x8 qf[8];
  {
    const unsigned short* qp = Qb + (rowbase + q0 + l31) * (long)ND + colbase + hi5 * 8;
#pragma unroll
    for (int kc = 0; kc < 8; ++kc) qf[kc] = *(const bf16x8*)(qp + kc * 16);
  }

  f32x16 oacc[4];
#pragma unroll
  for (int db = 0; db < 4; ++db)
#pragma unroll
    for (int i = 0; i < 16; ++i) oacc[db][i] = 0.f;
  float mrun = -1e30f, lrun = 0.f;

  // staging: thread covers keys (2kp, 2kp+1) at d-cols c8..c8+7
  const int kp = tid >> 4;                 // 0..31
  const int c8 = (tid & 15) * 8;
  bf16x8 kreg[2], vreg[2];

#define LOAD_KV(kt_) do {                                                          \
    _Pragma("unroll") for (int j = 0; j < 2; ++j) {                                \
      const long grow = (rowbase + (kt_) * 64 + 2 * kp + j) * (long)ND + colbase + c8; \
      kreg[j] = *(const bf16x8*)(Kb + grow);                                       \
      vreg[j] = *(const bf16x8*)(Vb + grow);                                       \
    } } while (0)

#define WRITE_KV(bi) do {                                                          \
    _Pragma("unroll") for (int j = 0; j < 2; ++j) {                                \
      int row_ = 2 * kp + j;                                                       \
      *(bf16x8*)(KsArr + (bi) * 8192 + row_ * 128 + (c8 ^ ((row_ & 15) << 3))) = kreg[j]; \
    }                                                                              \
    _Pragma("unroll") for (int i = 0; i < 8; ++i) {                                \
      int d_ = c8 + i;                                                             \
      VtArr[(bi) * 4608 + d_ * 36 + 4 * ((kp >> 2) ^ ((d_ >> 3) & 7)) + (kp & 3)] = \
          (unsigned int)(unsigned short)vreg[0][i] |                               \
          ((unsigned int)(unsigned short)vreg[1][i] << 16);                        \
    } } while (0)

  // prologue: tile 0 -> buf 0; then prefetch tile 1
  LOAD_KV(0);
  WRITE_KV(0);
  __syncthreads();
  LOAD_KV(1);

  const int NT = NL / 64;
  for (int kt = 0; kt < NT; ++kt) {
    const int bf = kt & 1;
    const unsigned short* Ksb = KsArr + bf * 8192;
    const unsigned int* Vtb = VtArr + bf * 4608;

    // 1. S^T = mfma32(K, Q) from buf bf
    f32x16 sacc[2];
    __builtin_amdgcn_s_setprio(1);
#pragma unroll
    for (int nb = 0; nb < 2; ++nb) {
#pragma unroll
      for (int i = 0; i < 16; ++i) sacc[nb][i] = 0.f;
#pragma unroll
      for (int kc = 0; kc < 8; ++kc) {
        int row = nb * 32 + l31;
        bf16x8 kf = *(const bf16x8*)(Ksb + row * 128 + ((kc * 16 + hi5 * 8) ^ ((row & 15) << 3)));
        sacc[nb] = __builtin_amdgcn_mfma_f32_32x32x16_bf16(kf, qf[kc], sacc[nb], 0, 0, 0);
      }
    }
    __builtin_amdgcn_s_setprio(0);

    // 2. stage tile kt+1 regs -> other buffer (overlaps softmax below)
    if (kt + 1 < NT) WRITE_KV(bf ^ 1);
    // 3. prefetch tile kt+2 -> regs
    if (kt + 2 < NT) LOAD_KV(kt + 2);

    // 4. lane-local online softmax (base-2; log2e pre-folded into Q scale), tree reduce
    float mxa[8];
#pragma unroll
    for (int i = 0; i < 8; ++i)
      mxa[i] = fmaxf(fmaxf(sacc[0][i], sacc[0][i + 8]), fmaxf(sacc[1][i], sacc[1][i + 8]));
    float mx = fmaxf(fmaxf(fmaxf(mxa[0], mxa[1]), fmaxf(mxa[2], mxa[3])),
                     fmaxf(fmaxf(mxa[4], mxa[5]), fmaxf(mxa[6], mxa[7])));
    mx = fmaxf(mx, __shfl_xor(mx, 32));
    if (!__all(mx - mrun <= 8.f)) {            // defer-max (T13)
      float mnew = fmaxf(mrun, mx);
      float corr = exp2_fast(mrun - mnew);
      mrun = mnew;
      lrun *= corr;
#pragma unroll
      for (int db = 0; db < 4; ++db)
#pragma unroll
        for (int i = 0; i < 16; ++i) oacc[db][i] *= corr;
    }
    float s4[4] = {0.f, 0.f, 0.f, 0.f};
#pragma unroll
    for (int nb = 0; nb < 2; ++nb)
#pragma unroll
      for (int r = 0; r < 16; ++r) {
        float e = exp2_fast(sacc[nb][r] - mrun);
        sacc[nb][r] = e;
        s4[r & 3] += e;
      }
    float s = (s4[0] + s4[1]) + (s4[2] + s4[3]);
    s += __shfl_xor(s, 32);
    lrun += s;

    // P -> B-operand frags: cvt_pk + permlane32_swap (T12), no LDS-pipe traffic
    union { unsigned int u[4]; bf16x8 v; } pa[2][2];
#pragma unroll
    for (int nb = 0; nb < 2; ++nb) {
      unsigned int x1 = cvtpk(sacc[nb][0], sacc[nb][1]);
      unsigned int x2 = cvtpk(sacc[nb][2], sacc[nb][3]);
      unsigned int y1 = cvtpk(sacc[nb][4], sacc[nb][5]);
      unsigned int y2 = cvtpk(sacc[nb][6], sacc[nb][7]);
      unsigned int z1 = cvtpk(sacc[nb][8], sacc[nb][9]);
      unsigned int z2 = cvtpk(sacc[nb][10], sacc[nb][11]);
      unsigned int w1 = cvtpk(sacc[nb][12], sacc[nb][13]);
      unsigned int w2 = cvtpk(sacc[nb][14], sacc[nb][15]);
      permswap(x1, y1);   // x1: u[0]; y1: u[2]
      permswap(x2, y2);
      permswap(z1, w1);
      permswap(z2, w2);
      pa[nb][0].u[0] = x1; pa[nb][0].u[1] = x2; pa[nb][0].u[2] = y1; pa[nb][0].u[3] = y2;
      pa[nb][1].u[0] = z1; pa[nb][1].u[1] = z2; pa[nb][1].u[2] = w1; pa[nb][1].u[3] = w2;
    }

    // 5. PV: O^T[d][q] += V^T-frag x P-frag from buf bf
    __builtin_amdgcn_s_setprio(1);
#pragma unroll
    for (int db = 0; db < 4; ++db) {
      int d = db * 32 + l31;
      int dsw = (d >> 3) & 7;
#pragma unroll
      for (int nb = 0; nb < 2; ++nb)
#pragma unroll
        for (int ks = 0; ks < 2; ++ks) {
          int g = nb * 4 + ks * 2 + hi5;
          bf16x8 vf = *(const bf16x8*)(Vtb + d * 36 + 4 * (g ^ dsw));
          oacc[db] = __builtin_amdgcn_mfma_f32_32x32x16_bf16(vf, pa[nb][ks].v, oacc[db], 0, 0, 0);
        }
    }
    __builtin_amdgcn_s_setprio(0);
    __syncthreads();   // buf bf free for overwrite; buf bf^1 writes visible
  }
#undef LOAD_KV
#undef WRITE_KV

  // ---------- epilogue: O^T -> O via per-wave LDS scratch (reuse VtArr), coalesced ----------
  float rinv = 1.0f / lrun;
  unsigned short* scr = (unsigned short*)VtArr + wid * 2304;   // 32 rows x 72
#pragma unroll
  for (int c = 0; c < 2; ++c) {          // d-chunks [0,64) and [64,128)
    asm volatile("s_waitcnt lgkmcnt(0)" ::: "memory");
    __builtin_amdgcn_sched_barrier(0);
#pragma unroll
    for (int dbh = 0; dbh < 2; ++dbh) {
      int db = 2 * c + dbh;
#pragma unroll
      for (int t = 0; t < 8; ++t) {
        int d_lo = dbh * 32 + ((2 * t) & 3) + 8 * (t >> 1) + 4 * hi5;
        unsigned int pv = cvtpk(oacc[db][2 * t] * rinv, oacc[db][2 * t + 1] * rinv);
        *(unsigned int*)(scr + l31 * 72 + d_lo) = pv;
      }
    }
    asm volatile("s_waitcnt lgkmcnt(0)" ::: "memory");
    __builtin_amdgcn_sched_barrier(0);
#pragma unroll
    for (int j = 0; j < 4; ++j) {
      int row = j * 8 + (lane >> 3);
      bf16x8 ov = *(const bf16x8*)(scr + row * 72 + (lane & 7) * 8);
      *(bf16x8*)(Ob + (rowbase + q0 + row) * (long)ND + colbase + c * 64 + (lane & 7) * 8) = ov;
    }
  }
}

// ---------------- launch ----------------
extern "C" void kernel_launch(void* const* d_in, const int* in_sizes, int n_in,
                              void* d_out, int out_size, void* d_ws, size_t ws_size,
                              hipStream_t stream) {
  const float* x = (const float*)d_in[0];
  const float* rope_cos = (const float*)d_in[1];
  const float* rope_sin = (const float*)d_in[2];
  const float* W_q = (const float*)d_in[3];
  const float* W_dkv = (const float*)d_in[4];
  const float* W_uk = (const float*)d_in[5];
  const float* W_uv = (const float*)d_in[6];
  const float* W_o = (const float*)d_in[7];
  float* out = (float*)d_out;

  char* p = (char*)d_ws;
  unsigned short* xb = (unsigned short*)p;    p += (size_t)NROWS * ND * 2;
  unsigned short* Wqb = (unsigned short*)p;   p += (size_t)ND * ND * 2;
  unsigned short* Wdkvb = (unsigned short*)p; p += (size_t)NDC * ND * 2;
  unsigned short* Wukb = (unsigned short*)p;  p += (size_t)ND * NDC * 2;
  unsigned short* Wuvb = (unsigned short*)p;  p += (size_t)ND * NDC * 2;
  unsigned short* Wob = (unsigned short*)p;   p += (size_t)ND * ND * 2;
  unsigned short* Qb = (unsigned short*)p;    p += (size_t)NROWS * ND * 2;
  unsigned short* ckv = (unsigned short*)p;   p += (size_t)NROWS * NDC * 2;
  unsigned short* Kbf = (unsigned short*)p;   p += (size_t)NROWS * ND * 2;
  unsigned short* Vbf = (unsigned short*)p;   p += (size_t)NROWS * ND * 2;
  unsigned short* AO = (unsigned short*)p;    p += (size_t)NROWS * ND * 2;

  // fp32 -> bf16 (six plain kernels — fused variant measured slower, r12)
  {
    struct { const float* s; unsigned short* d; long n; } cv[6] = {
      {x, xb, (long)NROWS * ND},
      {W_q, Wqb, (long)ND * ND},
      {W_dkv, Wdkvb, (long)NDC * ND},
      {W_uk, Wukb, (long)ND * NDC},
      {W_uv, Wuvb, (long)ND * NDC},
      {W_o, Wob, (long)ND * ND},
    };
    for (int i = 0; i < 6; ++i) {
      int n4 = (int)(cv[i].n / 4);
      int blocks = (n4 + 255) / 256;
      if (blocks > 2048) blocks = 2048;
      cvt_kernel<<<blocks, 256, 0, stream>>>((const float4*)cv[i].s, (ushort4*)cv[i].d, n4);
    }
  }

  // RoPE scales: Q gets 1/sqrt(DH)*log2(e) (flash softmax uses exp2); K gets 1.0
  const float scale_q = 0.08838834764831845f * 1.4426950408889634f;

  // projections (rope fused into Q and K epilogues)
  gemm_nt256<0, 1><<<dim3(ND / 256, NROWS / 256), 512, 0, stream>>>(
      xb, Wqb, Qb, NROWS, ND, ND, rope_cos, rope_sin, scale_q);
  gemm_nt<0><<<dim3(NDC / 128, NROWS / 128), 256, 0, stream>>>(xb, Wdkvb, ckv, NROWS, NDC, ND);
  gemm_nt256<0, 1><<<dim3(ND / 256, NROWS / 256), 512, 0, stream>>>(
      ckv, Wukb, Kbf, NROWS, ND, NDC, rope_cos, rope_sin, 1.0f);
  gemm_nt256<0, 0><<<dim3(ND / 256, NROWS / 256), 512, 0, stream>>>(
      ckv, Wuvb, Vbf, NROWS, ND, NDC, nullptr, nullptr, 0.f);

  // attention: 512 blocks of 512 threads (QBLK=256, 32 q/wave) — proven v8 config
  flash_attn<<<dim3(8, 64), 512, 0, stream>>>(Qb, Kbf, Vbf, AO);

  // output projection (fp32 out)
  gemm_nt256<1, 0><<<dim3(ND / 256, NROWS / 256), 512, 0, stream>>>(
      AO, Wob, out, NROWS, ND, ND, nullptr, nullptr, 0.f);
}

// Round 14
// 421.838 us; speedup vs baseline: 1.6648x; 1.0049x over previous
//
#include <hip/hip_runtime.h>
#include <math.h>

typedef __attribute__((ext_vector_type(8))) short bf16x8;
typedef __attribute__((ext_vector_type(4))) float f32x4;
typedef __attribute__((ext_vector_type(16))) float f32x16;

#define NB 4
#define NL 2048
#define ND 2048
#define NH 16
#define NDH 128
#define NDC 512
#define NROWS (NB*NL)

__device__ __forceinline__ unsigned short f2bf(float f) {
  unsigned int u = __float_as_uint(f);
  u += 0x7fffu + ((u >> 16) & 1u);
  return (unsigned short)(u >> 16);
}
__device__ __forceinline__ float bf2f(unsigned short h) {
  return __uint_as_float(((unsigned int)h) << 16);
}
__device__ __forceinline__ unsigned int cvtpk(float lo, float hi) {
  unsigned int r;
  asm("v_cvt_pk_bf16_f32 %0, %1, %2" : "=v"(r) : "v"(lo), "v"(hi));
  return r;
}
// v_permlane32_swap_b32: a.lanes[32:63] <-> b.lanes[0:31]
__device__ __forceinline__ void permswap(unsigned int &a, unsigned int &b) {
  asm("v_permlane32_swap_b32 %0, %1" : "+v"(a), "+v"(b));
}
__device__ __forceinline__ float exp2_fast(float x) {
  float r; asm("v_exp_f32 %0, %1" : "=v"(r) : "v"(x)); return r;
}

__device__ __forceinline__ void gld16(const void* g, void* l) {
  __builtin_amdgcn_global_load_lds((const __attribute__((address_space(1))) void*)g,
                                   (__attribute__((address_space(3))) void*)l, 16, 0, 0);
}

// ---------------- fused fp32 -> bf16 convert: blockIdx.y = segment (no search) ----------------
struct Cvt6 {
  const float4* s[6];
  ushort4* d[6];
  int n4[6];
};
__global__ void cvt6_kernel(Cvt6 cv) {
  const int seg = blockIdx.y;
  const float4* __restrict__ in = cv.s[seg];
  ushort4* __restrict__ out = cv.d[seg];
  const int n4 = cv.n4[seg];
  int stride = gridDim.x * blockDim.x;
  for (int i = blockIdx.x * blockDim.x + threadIdx.x; i < n4; i += stride) {
    float4 v = in[i];
    ushort4 o;
    o.x = f2bf(v.x); o.y = f2bf(v.y); o.z = f2bf(v.z); o.w = f2bf(v.w);
    out[i] = o;
  }
}

// ---------------- 128^2 NT GEMM (kept for N=512 shapes) ----------------
template<int OUT_F32>
__global__ __launch_bounds__(256) void gemm_nt(const unsigned short* __restrict__ A,
                                               const unsigned short* __restrict__ Bm,
                                               void* __restrict__ Cv,
                                               int M, int N, int K) {
  __shared__ unsigned short As[128 * 32];
  __shared__ unsigned short Bs[128 * 32];
  const int tid = threadIdx.x;
  const int wid = tid >> 6;
  const int lane = tid & 63;
  const int wr = wid >> 1, wc = wid & 1;
  const long bm = blockIdx.y, bn = blockIdx.x;
  const int r15 = lane & 15;
  const int koff = (lane >> 4) * 8;
  const int srow = lane >> 2;
  const int scol = (lane & 3) * 8;

  f32x4 acc[4][4];
#pragma unroll
  for (int m = 0; m < 4; ++m)
#pragma unroll
    for (int n = 0; n < 4; ++n) acc[m][n] = (f32x4){0.f, 0.f, 0.f, 0.f};

  const unsigned short* Ablk = A + (bm * 128 + wid * 16 + srow) * (long)K + scol;
  const unsigned short* Bblk = Bm + (bn * 128 + wid * 16 + srow) * (long)K + scol;
  unsigned short* AsW = As + wid * 16 * 32;
  unsigned short* BsW = Bs + wid * 16 * 32;

  for (int kk = 0; kk < K; kk += 32) {
    __syncthreads();
#pragma unroll
    for (int j = 0; j < 2; ++j) {
      gld16(Ablk + (long)j * 64 * K + kk, AsW + j * 64 * 32);
      gld16(Bblk + (long)j * 64 * K + kk, BsW + j * 64 * 32);
    }
    __syncthreads();
    bf16x8 af[4], bfr[4];
#pragma unroll
    for (int m = 0; m < 4; ++m)
      af[m] = *(const bf16x8*)(As + (wr * 64 + m * 16 + r15) * 32 + koff);
#pragma unroll
    for (int n = 0; n < 4; ++n)
      bfr[n] = *(const bf16x8*)(Bs + (wc * 64 + n * 16 + r15) * 32 + koff);
#pragma unroll
    for (int m = 0; m < 4; ++m)
#pragma unroll
      for (int n = 0; n < 4; ++n)
        acc[m][n] = __builtin_amdgcn_mfma_f32_16x16x32_bf16(af[m], bfr[n], acc[m][n], 0, 0, 0);
  }

  const int rr = (lane >> 4) * 4;
#pragma unroll
  for (int m = 0; m < 4; ++m) {
#pragma unroll
    for (int n = 0; n < 4; ++n) {
      long row0 = bm * 128 + wr * 64 + m * 16 + rr;
      long col = bn * 128 + wc * 64 + n * 16 + r15;
#pragma unroll
      for (int r = 0; r < 4; ++r) {
        float v = acc[m][n][r];
        if (OUT_F32) ((float*)Cv)[(row0 + r) * (long)N + col] = v;
        else ((unsigned short*)Cv)[(row0 + r) * (long)N + col] = f2bf(v);
      }
    }
  }
}

// ---------------- 256^2 8-phase NT GEMM (T1+T2+T3+T4+T5) ----------------
// bf16 out: LDS-staged coalesced epilogue, optional fused RoPE.
// f32 out: two-pass LDS-staged coalesced epilogue (128x256 f32 = 128KB per pass).
template<int OUT_F32, int ROPE>
__global__ __launch_bounds__(512) void gemm_nt256(const unsigned short* __restrict__ A,
                                                  const unsigned short* __restrict__ Bm,
                                                  void* __restrict__ Cv,
                                                  int M, int N, int K,
                                                  const float* __restrict__ cosb,
                                                  const float* __restrict__ sinb,
                                                  float rscale) {
  __shared__ unsigned short lds[2][2][16384];   // [buf][0=A,1=B][256 rows x 64 cols]
  const int tid = threadIdx.x;
  const int wid = tid >> 6, lane = tid & 63;
  const int wm = wid >> 2, wn = wid & 3;
  const int r15 = lane & 15, khi = lane >> 4;

  const int gx = gridDim.x;
  int bid = blockIdx.y * gx + blockIdx.x;
  int cpx = (gx * gridDim.y) >> 3;
  int swz = (bid & 7) * cpx + (bid >> 3);
  const long bm = swz / gx, bn = swz % gx;

  const int c0 = tid, c1 = 512 + tid;
  const int r0 = c0 >> 3, r1 = c1 >> 3;
  const int cs0 = ((c0 & 7) ^ (r0 & 7)) * 8;
  const int cs1 = ((c1 & 7) ^ (r1 & 7)) * 8;
  const unsigned short* srcA = A + (bm * 256) * (long)K;
  const unsigned short* srcB = Bm + (bn * 256) * (long)K;

#define STAGE256(mat, h, kb, bufi) do {                                              \
    const unsigned short* s_ = (mat) ? srcB : srcA;                                  \
    gld16(s_ + ((h) * 128 + r0) * (long)K + (kb) + cs0,                              \
          &lds[bufi][mat][(h) * 8192 + wid * 512]);                                  \
    gld16(s_ + ((h) * 128 + r1) * (long)K + (kb) + cs1,                              \
          &lds[bufi][mat][(h) * 8192 + 4096 + wid * 512]);                           \
  } while (0)

  f32x4 acc[8][4];
#pragma unroll
  for (int m = 0; m < 8; ++m)
#pragma unroll
    for (int n = 0; n < 4; ++n) acc[m][n] = (f32x4){0.f, 0.f, 0.f, 0.f};

  const int NT = K >> 6;
  STAGE256(0, 0, 0, 0); STAGE256(0, 1, 0, 0);
  STAGE256(1, 0, 0, 0); STAGE256(1, 1, 0, 0);

  for (int t = 0; t < NT; ++t) {
    const int buf = t & 1, nbuf = buf ^ 1;
    const int kb1 = (t + 1) << 6;
    const bool pf = (t + 1 < NT);
    __builtin_amdgcn_s_barrier();
    if (pf) {
      STAGE256(0, 0, kb1, nbuf);
      asm volatile("s_waitcnt vmcnt(2)" ::: "memory");
    } else {
      asm volatile("s_waitcnt vmcnt(0)" ::: "memory");
    }
    __builtin_amdgcn_s_barrier();

    bf16x8 bfr[4][2];
#pragma unroll
    for (int n = 0; n < 4; ++n)
#pragma unroll
      for (int kk = 0; kk < 2; ++kk) {
        int rb = wn * 64 + n * 16 + r15;
        bfr[n][kk] = *(const bf16x8*)&lds[buf][1][rb * 64 + (((kk * 4 + khi) ^ (rb & 7)) * 8)];
      }
#pragma unroll
    for (int mb = 0; mb < 4; ++mb) {
      if (mb != 0) {
        __builtin_amdgcn_s_barrier();
        if (pf) {
          if (mb == 1) STAGE256(0, 1, kb1, nbuf);
          else if (mb == 2) STAGE256(1, 0, kb1, nbuf);
          else STAGE256(1, 1, kb1, nbuf);
        }
      }
      bf16x8 af[2][2];
#pragma unroll
      for (int m2 = 0; m2 < 2; ++m2)
#pragma unroll
        for (int kk = 0; kk < 2; ++kk) {
          int ra = wm * 128 + mb * 32 + m2 * 16 + r15;
          af[m2][kk] = *(const bf16x8*)&lds[buf][0][ra * 64 + (((kk * 4 + khi) ^ (ra & 7)) * 8)];
        }
      asm volatile("s_waitcnt lgkmcnt(0)" ::: "memory");
      __builtin_amdgcn_sched_barrier(0);
      __builtin_amdgcn_s_setprio(1);
#pragma unroll
      for (int m2 = 0; m2 < 2; ++m2)
#pragma unroll
        for (int n = 0; n < 4; ++n)
#pragma unroll
          for (int kk = 0; kk < 2; ++kk)
            acc[mb * 2 + m2][n] = __builtin_amdgcn_mfma_f32_16x16x32_bf16(
                af[m2][kk], bfr[n][kk], acc[mb * 2 + m2][n], 0, 0, 0);
      __builtin_amdgcn_s_setprio(0);
    }
  }
#undef STAGE256

  if (!OUT_F32) {
    // ---- LDS-staged bf16 epilogue (coalesced), optional rotary ----
    __syncthreads();
    unsigned short* scr = (unsigned short*)lds;   // col ^ ((row>>2)&3)<<4 swizzle
#pragma unroll
    for (int mi = 0; mi < 8; ++mi)
#pragma unroll
      for (int n = 0; n < 4; ++n) {
        int coll = wn * 64 + n * 16 + r15;
#pragma unroll
        for (int r = 0; r < 4; ++r) {
          int rowl = wm * 128 + mi * 16 + khi * 4 + r;
          scr[rowl * 256 + (coll ^ (((rowl >> 2) & 3) << 4))] = f2bf(acc[mi][n][r]);
        }
      }
    __syncthreads();
    const int d8 = (tid & 7) * 8;
#pragma unroll
    for (int j = 0; j < 8; ++j) {
      int rh = j * 64 + (tid >> 3);
      int rowl = rh >> 1, head = rh & 1;
      long grow = bm * 256 + rowl;
      int sw = ((rowl >> 2) & 3) << 4;
      int cl_ = head * 128 + d8;
      bf16x8 qlo = *(const bf16x8*)(scr + rowl * 256 + (cl_ ^ sw));
      bf16x8 qhi = *(const bf16x8*)(scr + rowl * 256 + ((cl_ + 64) ^ sw));
      bf16x8 olo, ohi;
      if (ROPE) {
        const float* cr = cosb + grow * NDH;
        const float* sr = sinb + grow * NDH;
        float4 cA = *(const float4*)(cr + d8), cB = *(const float4*)(cr + d8 + 4);
        float4 cC = *(const float4*)(cr + d8 + 64), cD = *(const float4*)(cr + d8 + 68);
        float4 sA = *(const float4*)(sr + d8), sB = *(const float4*)(sr + d8 + 4);
        float4 sC = *(const float4*)(sr + d8 + 64), sD = *(const float4*)(sr + d8 + 68);
        float clo[8] = {cA.x, cA.y, cA.z, cA.w, cB.x, cB.y, cB.z, cB.w};
        float chi[8] = {cC.x, cC.y, cC.z, cC.w, cD.x, cD.y, cD.z, cD.w};
        float slo[8] = {sA.x, sA.y, sA.z, sA.w, sB.x, sB.y, sB.z, sB.w};
        float shi[8] = {sC.x, sC.y, sC.z, sC.w, sD.x, sD.y, sD.z, sD.w};
#pragma unroll
        for (int i = 0; i < 8; ++i) {
          float q1 = bf2f((unsigned short)qlo[i]);
          float q2 = bf2f((unsigned short)qhi[i]);
          olo[i] = (short)f2bf((q1 * clo[i] - q2 * slo[i]) * rscale);
          ohi[i] = (short)f2bf((q2 * chi[i] + q1 * shi[i]) * rscale);
        }
      } else {
        olo = qlo;
        ohi = qhi;
      }
      unsigned short* op = (unsigned short*)Cv + grow * (long)N + bn * 256 + cl_;
      *(bf16x8*)op = olo;
      *(bf16x8*)(op + 64) = ohi;
    }
  } else {
    // ---- two-pass LDS-staged f32 epilogue (coalesced 1KB/wave stores) ----
    float* scr32 = (float*)lds;   // 128 rows x 256 cols f32 = 128KB
#pragma unroll
    for (int pass = 0; pass < 2; ++pass) {
      __syncthreads();
      if (wm == pass) {
#pragma unroll
        for (int mi = 0; mi < 8; ++mi)
#pragma unroll
          for (int n = 0; n < 4; ++n) {
            int coll = wn * 64 + n * 16 + r15;
#pragma unroll
            for (int r = 0; r < 4; ++r) {
              int rowl = mi * 16 + khi * 4 + r;    // 0..127 within half
              scr32[rowl * 256 + (coll ^ (((rowl >> 2) & 3) << 4))] = acc[mi][n][r];
            }
          }
      }
      __syncthreads();
#pragma unroll
      for (int j = 0; j < 16; ++j) {
        int rowl = j * 8 + wid;
        int sw = ((rowl >> 2) & 3) << 4;
        float4 v = *(const float4*)(scr32 + rowl * 256 + ((lane * 4) ^ sw));
        *(float4*)((float*)Cv + (bm * 256 + pass * 128 + rowl) * (long)N + bn * 256 + lane * 4) = v;
      }
    }
  }
}

// ---------------- Flash attention v8 (proven config, unchanged) ----------------
__global__ __launch_bounds__(512) void flash_attn(const unsigned short* __restrict__ Qb,
                                                  const unsigned short* __restrict__ Kb,
                                                  const unsigned short* __restrict__ Vb,
                                                  unsigned short* __restrict__ Ob) {
  __shared__ unsigned short KsArr[2 * 8192];   // [buf][key*128 + (c ^ ((key&15)<<3))]
  __shared__ unsigned int VtArr[2 * 4608];     // [buf][d*36 + 4*((kp>>2)^((d>>3)&7)) + (kp&3)]

  const int tid = threadIdx.x, wid = tid >> 6, lane = tid & 63;
  const int l31 = lane & 31, hi5 = lane >> 5;

  const int L = blockIdx.y * 8 + blockIdx.x;
  const int bh = ((L >> 6) << 3) | (L & 7);
  const int qt = (L >> 3) & 7;
  const int b = bh >> 4, h = bh & 15;
  const long rowbase = (long)b * NL;
  const int colbase = h * NDH;
  const long q0 = (long)qt * 256 + wid * 32;

  bf16x8 qf[8];
  {
    const unsigned short* qp = Qb + (rowbase + q0 + l31) * (long)ND + colbase + hi5 * 8;
#pragma unroll
    for (int kc = 0; kc < 8; ++kc) qf[kc] = *(const bf16x8*)(qp + kc * 16);
  }

  f32x16 oacc[4];
#pragma unroll
  for (int db = 0; db < 4; ++db)
#pragma unroll
    for (int i = 0; i < 16; ++i) oacc[db][i] = 0.f;
  float mrun = -1e30f, lrun = 0.f;

  const int kp = tid >> 4;                 // 0..31
  const int c8 = (tid & 15) * 8;
  bf16x8 kreg[2], vreg[2];

#define LOAD_KV(kt_) do {                                                          \
    _Pragma("unroll") for (int j = 0; j < 2; ++j) {                                \
      const long grow = (rowbase + (kt_) * 64 + 2 * kp + j) * (long)ND + colbase + c8; \
      kreg[j] = *(const bf16x8*)(Kb + grow);                                       \
      vreg[j] = *(const bf16x8*)(Vb + grow);                                       \
    } } while (0)

#define WRITE_KV(bi) do {                                                          \
    _Pragma("unroll") for (int j = 0; j < 2; ++j) {                                \
      int row_ = 2 * kp + j;                                                       \
      *(bf16x8*)(KsArr + (bi) * 8192 + row_ * 128 + (c8 ^ ((row_ & 15) << 3))) = kreg[j]; \
    }                                                                              \
    _Pragma("unroll") for (int i = 0; i < 8; ++i) {                                \
      int d_ = c8 + i;                                                             \
      VtArr[(bi) * 4608 + d_ * 36 + 4 * ((kp >> 2) ^ ((d_ >> 3) & 7)) + (kp & 3)] = \
          (unsigned int)(unsigned short)vreg[0][i] |                               \
          ((unsigned int)(unsigned short)vreg[1][i] << 16);                        \
    } } while (0)

  LOAD_KV(0);
  WRITE_KV(0);
  __syncthreads();
  LOAD_KV(1);

  const int NT = NL / 64;
  for (int kt = 0; kt < NT; ++kt) {
    const int bf = kt & 1;
    const unsigned short* Ksb = KsArr + bf * 8192;
    const unsigned int* Vtb = VtArr + bf * 4608;

    f32x16 sacc[2];
    __builtin_amdgcn_s_setprio(1);
#pragma unroll
    for (int nb = 0; nb < 2; ++nb) {
#pragma unroll
      for (int i = 0; i < 16; ++i) sacc[nb][i] = 0.f;
#pragma unroll
      for (int kc = 0; kc < 8; ++kc) {
        int row = nb * 32 + l31;
        bf16x8 kf = *(const bf16x8*)(Ksb + row * 128 + ((kc * 16 + hi5 * 8) ^ ((row & 15) << 3)));
        sacc[nb] = __builtin_amdgcn_mfma_f32_32x32x16_bf16(kf, qf[kc], sacc[nb], 0, 0, 0);
      }
    }
    __builtin_amdgcn_s_setprio(0);

    if (kt + 1 < NT) WRITE_KV(bf ^ 1);
    if (kt + 2 < NT) LOAD_KV(kt + 2);

    float mxa[8];
#pragma unroll
    for (int i = 0; i < 8; ++i)
      mxa[i] = fmaxf(fmaxf(sacc[0][i], sacc[0][i + 8]), fmaxf(sacc[1][i], sacc[1][i + 8]));
    float mx = fmaxf(fmaxf(fmaxf(mxa[0], mxa[1]), fmaxf(mxa[2], mxa[3])),
                     fmaxf(fmaxf(mxa[4], mxa[5]), fmaxf(mxa[6], mxa[7])));
    mx = fmaxf(mx, __shfl_xor(mx, 32));
    if (!__all(mx - mrun <= 8.f)) {            // defer-max (T13)
      float mnew = fmaxf(mrun, mx);
      float corr = exp2_fast(mrun - mnew);
      mrun = mnew;
      lrun *= corr;
#pragma unroll
      for (int db = 0; db < 4; ++db)
#pragma unroll
        for (int i = 0; i < 16; ++i) oacc[db][i] *= corr;
    }
    float s4[4] = {0.f, 0.f, 0.f, 0.f};
#pragma unroll
    for (int nb = 0; nb < 2; ++nb)
#pragma unroll
      for (int r = 0; r < 16; ++r) {
        float e = exp2_fast(sacc[nb][r] - mrun);
        sacc[nb][r] = e;
        s4[r & 3] += e;
      }
    float s = (s4[0] + s4[1]) + (s4[2] + s4[3]);
    s += __shfl_xor(s, 32);
    lrun += s;

    union { unsigned int u[4]; bf16x8 v; } pa[2][2];
#pragma unroll
    for (int nb = 0; nb < 2; ++nb) {
      unsigned int x1 = cvtpk(sacc[nb][0], sacc[nb][1]);
      unsigned int x2 = cvtpk(sacc[nb][2], sacc[nb][3]);
      unsigned int y1 = cvtpk(sacc[nb][4], sacc[nb][5]);
      unsigned int y2 = cvtpk(sacc[nb][6], sacc[nb][7]);
      unsigned int z1 = cvtpk(sacc[nb][8], sacc[nb][9]);
      unsigned int z2 = cvtpk(sacc[nb][10], sacc[nb][11]);
      unsigned int w1 = cvtpk(sacc[nb][12], sacc[nb][13]);
      unsigned int w2 = cvtpk(sacc[nb][14], sacc[nb][15]);
      permswap(x1, y1);
      permswap(x2, y2);
      permswap(z1, w1);
      permswap(z2, w2);
      pa[nb][0].u[0] = x1; pa[nb][0].u[1] = x2; pa[nb][0].u[2] = y1; pa[nb][0].u[3] = y2;
      pa[nb][1].u[0] = z1; pa[nb][1].u[1] = z2; pa[nb][1].u[2] = w1; pa[nb][1].u[3] = w2;
    }

    __builtin_amdgcn_s_setprio(1);
#pragma unroll
    for (int db = 0; db < 4; ++db) {
      int d = db * 32 + l31;
      int dsw = (d >> 3) & 7;
#pragma unroll
      for (int nb = 0; nb < 2; ++nb)
#pragma unroll
        for (int ks = 0; ks < 2; ++ks) {
          int g = nb * 4 + ks * 2 + hi5;
          bf16x8 vf = *(const bf16x8*)(Vtb + d * 36 + 4 * (g ^ dsw));
          oacc[db] = __builtin_amdgcn_mfma_f32_32x32x16_bf16(vf, pa[nb][ks].v, oacc[db], 0, 0, 0);
        }
    }
    __builtin_amdgcn_s_setprio(0);
    __syncthreads();
  }
#undef LOAD_KV
#undef WRITE_KV

  float rinv = 1.0f / lrun;
  unsigned short* scr = (unsigned short*)VtArr + wid * 2304;   // 32 rows x 72
#pragma unroll
  for (int c = 0; c < 2; ++c) {
    asm volatile("s_waitcnt lgkmcnt(0)" ::: "memory");
    __builtin_amdgcn_sched_barrier(0);
#pragma unroll
    for (int dbh = 0; dbh < 2; ++dbh) {
      int db = 2 * c + dbh;
#pragma unroll
      for (int t = 0; t < 8; ++t) {
        int d_lo = dbh * 32 + ((2 * t) & 3) + 8 * (t >> 1) + 4 * hi5;
        unsigned int pv = cvtpk(oacc[db][2 * t] * rinv, oacc[db][2 * t + 1] * rinv);
        *(unsigned int*)(scr + l31 * 72 + d_lo) = pv;
      }
    }
    asm volatile("s_waitcnt lgkmcnt(0)" ::: "memory");
    __builtin_amdgcn_sched_barrier(0);
#pragma unroll
    for (int j = 0; j < 4; ++j) {
      int row = j * 8 + (lane >> 3);
      bf16x8 ov = *(const bf16x8*)(scr + row * 72 + (lane & 7) * 8);
      *(bf16x8*)(Ob + (rowbase + q0 + row) * (long)ND + colbase + c * 64 + (lane & 7) * 8) = ov;
    }
  }
}

// ---------------- launch ----------------
extern "C" void kernel_launch(void* const* d_in, const int* in_sizes, int n_in,
                              void* d_out, int out_size, void* d_ws, size_t ws_size,
                              hipStream_t stream) {
  const float* x = (const float*)d_in[0];
  const float* rope_cos = (const float*)d_in[1];
  const float* rope_sin = (const float*)d_in[2];
  const float* W_q = (const float*)d_in[3];
  const float* W_dkv = (const float*)d_in[4];
  const float* W_uk = (const float*)d_in[5];
  const float* W_uv = (const float*)d_in[6];
  const float* W_o = (const float*)d_in[7];
  float* out = (float*)d_out;

  char* p = (char*)d_ws;
  unsigned short* xb = (unsigned short*)p;    p += (size_t)NROWS * ND * 2;
  unsigned short* Wqb = (unsigned short*)p;   p += (size_t)ND * ND * 2;
  unsigned short* Wdkvb = (unsigned short*)p; p += (size_t)NDC * ND * 2;
  unsigned short* Wukb = (unsigned short*)p;  p += (size_t)ND * NDC * 2;
  unsigned short* Wuvb = (unsigned short*)p;  p += (size_t)ND * NDC * 2;
  unsigned short* Wob = (unsigned short*)p;   p += (size_t)ND * ND * 2;
  unsigned short* Qb = (unsigned short*)p;    p += (size_t)NROWS * ND * 2;
  unsigned short* ckv = (unsigned short*)p;   p += (size_t)NROWS * NDC * 2;
  unsigned short* Kbf = (unsigned short*)p;   p += (size_t)NROWS * ND * 2;
  unsigned short* Vbf = (unsigned short*)p;   p += (size_t)NROWS * ND * 2;
  unsigned short* AO = (unsigned short*)p;    p += (size_t)NROWS * ND * 2;

  // fused fp32 -> bf16: one dispatch, blockIdx.y = segment
  {
    Cvt6 cv;
    const float* ss[6] = {x, W_q, W_dkv, W_uk, W_uv, W_o};
    unsigned short* dd[6] = {xb, Wqb, Wdkvb, Wukb, Wuvb, Wob};
    long nn[6] = {(long)NROWS * ND, (long)ND * ND, (long)NDC * ND,
                  (long)ND * NDC, (long)ND * NDC, (long)ND * ND};
    for (int i = 0; i < 6; ++i) {
      cv.s[i] = (const float4*)ss[i];
      cv.d[i] = (ushort4*)dd[i];
      cv.n4[i] = (int)(nn[i] / 4);
    }
    cvt6_kernel<<<dim3(512, 6), 256, 0, stream>>>(cv);
  }

  // RoPE scales: Q gets 1/sqrt(DH)*log2(e) (flash softmax uses exp2); K gets 1.0
  const float scale_q = 0.08838834764831845f * 1.4426950408889634f;

  // projections (rope fused into Q and K epilogues)
  gemm_nt256<0, 1><<<dim3(ND / 256, NROWS / 256), 512, 0, stream>>>(
      xb, Wqb, Qb, NROWS, ND, ND, rope_cos, rope_sin, scale_q);
  gemm_nt<0><<<dim3(NDC / 128, NROWS / 128), 256, 0, stream>>>(xb, Wdkvb, ckv, NROWS, NDC, ND);
  gemm_nt256<0, 1><<<dim3(ND / 256, NROWS / 256), 512, 0, stream>>>(
      ckv, Wukb, Kbf, NROWS, ND, NDC, rope_cos, rope_sin, 1.0f);
  gemm_nt256<0, 0><<<dim3(ND / 256, NROWS / 256), 512, 0, stream>>>(
      ckv, Wuvb, Vbf, NROWS, ND, NDC, nullptr, nullptr, 0.f);

  // attention: 512 blocks of 512 threads (QBLK=256, 32 q/wave) — proven v8 config
  flash_attn<<<dim3(8, 64), 512, 0, stream>>>(Qb, Kbf, Vbf, AO);

  // output projection (fp32 out, coalesced LDS epilogue)
  gemm_nt256<1, 0><<<dim3(ND / 256, NROWS / 256), 512, 0, stream>>>(
      AO, Wob, out, NROWS, ND, ND, nullptr, nullptr, 0.f);
}